// Round 7
// baseline (8586.664 us; speedup 1.0000x reference)
//
#include <hip/hip_runtime.h>
#include <stdint.h>

// ---------------------------------------------------------------------------
// RNN rollout. Phase 1: teacher-forced recurrence + bulk batched psi. Phase 2:
// persistent AR kernel, 8 groups x 32 members, member m -> XCD m%8 (weight
// slices L2-resident, R6/R8). Failed variants (do not retry): co-located
// groups (R9), in-grid psi fusion (R11), redundant full-L1 (R12), epoch-flag
// exchange (R13). R14 (4800us steady): ARRIVE/overlap/WAIT barrier split +
// cell z-part overlap + one less syncthreads per hop.
// R15: hop 4 restructured -- distributed L5 with MALL f32 atomic reduction:
//   - each member computes L5 PARTIAL from its own h4 slice (K=32, 1 MFMA
//     per wave) and atomic-adds the 16x32 f32 tile into a parity-buffered
//     2KB accumulator at MALL (512 words x 32 adds, fire-and-forget).
//   - h4 publish + 32KB h4 DMA + tail's redundant 32-MFMA L5: all deleted.
//     Readback is a 2KB DMA. Accumulator zeroed by wave0 after hop-1 WAIT
//     (parity t+1; ordered by the hop-2 arrive drain + barrier chain).
// Sizes fixed: B=128, T=256, HOR=512, OBS=32, LAT=256, HID=1024.
// ---------------------------------------------------------------------------

#define BATCH 128
#define TTF   256
#define HOR   512
#define OBS   32
#define LAT   256
#define HID   1024

#define GROUPS  8
#define MEMBERS 32
#define ARBLOCKS (GROUPS * MEMBERS)
#define ARTHREADS 128

typedef __attribute__((ext_vector_type(8))) short short8;
typedef __attribute__((ext_vector_type(4))) float floatx4;

// ---- workspace layout (bytes) ----
#define OFF_WB1   ((size_t)0)                          // 1024x256 bf16 ([col][k])
#define OFF_WB2   (OFF_WB1 + (size_t)HID*LAT*2)        // 1024x1024 bf16
#define OFF_WB3   (OFF_WB2 + (size_t)HID*HID*2)
#define OFF_WB4   (OFF_WB3 + (size_t)HID*HID*2)
#define OFF_WB5   (OFF_WB4 + (size_t)HID*HID*2)        // 32x1024 bf16
#define OFF_CB    (OFF_WB5 + (size_t)OBS*HID*2)        // 256 f32 (b_ih+b_hh)
#define OFF_WHH2  (OFF_CB + (size_t)LAT*4)             // 64x256 uint2 packed W_hh^T
#define OFF_WIH2  (OFF_WHH2 + (size_t)64*256*8)        // 8x256 uint2 packed W_ih^T
#define OFF_ZF    (OFF_WIH2 + (size_t)8*256*8)         // 128x256 f32
#define OFF_Z     (OFF_ZF + (size_t)BATCH*LAT*4)       // 32768x256 bf16
#define OFF_WBC   (OFF_Z + (size_t)BATCH*TTF*LAT*2)    // 256x288 bf16 cell matrix
#define OFF_HB    (OFF_WBC + (size_t)LAT*288*2)        // 8 x 2par x 4 x 16x1024 bf16
#define OFF_CTR   (OFF_HB + (size_t)GROUPS*8*16*HID*2) // 8 x 512B counters
#define OFF_YH    (OFF_CTR + (size_t)GROUPS*512)       // 8 x 2par x 512 f32 (4KB/group)
#define OFF_END   (OFF_YH + (size_t)GROUPS*4096)

__device__ __forceinline__ uint16_t f2bf(float f) {
    uint32_t u = __float_as_uint(f);
    u += 0x7fffu + ((u >> 16) & 1u);   // RNE
    return (uint16_t)(u >> 16);
}
__device__ __forceinline__ float bflo(uint32_t u) { return __uint_as_float(u << 16); }
__device__ __forceinline__ float bfhi(uint32_t u) { return __uint_as_float(u & 0xffff0000u); }

__device__ __forceinline__ float fast_tanh(float x) {
    float ax = fabsf(x);
    float e  = __expf(-2.f * ax);
    float r  = (1.f - e) / (1.f + e);
    return copysignf(r, x);
}

// XOR-granule swizzles (16B granule index ^ low bits of row). Producers store
// swizzled; the verbatim DMA lands swizzled in LDS; readers XOR back.
__device__ __forceinline__ int hswz(int row, int col) {   // h: stride 1024
    return row * 1024 + ((((col >> 3) ^ (row & 7)) << 3) | (col & 7));
}
__device__ __forceinline__ int zswz(int row, int col) {   // z: stride 256
    return row * 256 + ((((col >> 3) ^ (row & 7)) << 3) | (col & 7));
}

// 16B MALL-coherent store (sc0|sc1 write-through, proven R9/R10).
__device__ __forceinline__ void st16_mall(void* p, floatx4 v) {
    asm volatile("global_store_dwordx4 %0, %1, off sc0 sc1"
                 :: "v"(p), "v"(v) : "memory");
}

// async DMA global->LDS, 16 B/lane, aux=0x11 (CPol SC0|SC1): reads at MALL
// (coherent with the sc0|sc1 writers and MALL atomics), no L1/L2 alloc.
typedef const __attribute__((address_space(1))) void* gas_t;
typedef __attribute__((address_space(3))) void* las_t;
__device__ __forceinline__ void gl_lds16(const void* g, void* l) {
    __builtin_amdgcn_global_load_lds((gas_t)g, (las_t)l, 16, 0, 0x11);
}

// 32 KB h tile MALL -> LDS: per wave 16 issues x 1 KB, all in flight.
__device__ __forceinline__ void stage_h(const uint16_t* src, uint16_t* dst,
                                        int w, int L) {
    const char* gp = (const char*)src + w * 16384 + L * 16;
    char* lp = (char*)dst + w * 16384;
    #pragma unroll
    for (int i = 0; i < 16; i++)
        gl_lds16(gp + i * 1024, lp + i * 1024);
}

// ---------------------------------------------------------------------------
// K0 helpers
// ---------------------------------------------------------------------------
__global__ void k_cvt(const float* __restrict__ s, uint16_t* __restrict__ d, int n) {
    int i = blockIdx.x * 256 + threadIdx.x;
    if (i < n) d[i] = f2bf(s[i]);
}

__global__ void k_cb(const float* __restrict__ a, const float* __restrict__ b,
                     float* __restrict__ c) {
    int j = threadIdx.x;
    c[j] = a[j] + b[j];
}

__global__ void k_pack(const float* __restrict__ w, uint2* __restrict__ dst, int klen) {
    int k4 = blockIdx.x, j = threadIdx.x;
    int k = k4 * 4;
    uint32_t a = f2bf(w[(size_t)j * klen + k + 0]);
    uint32_t b = f2bf(w[(size_t)j * klen + k + 1]);
    uint32_t c = f2bf(w[(size_t)j * klen + k + 2]);
    uint32_t d = f2bf(w[(size_t)j * klen + k + 3]);
    uint2 r; r.x = a | (b << 16); r.y = c | (d << 16);
    dst[k4 * 256 + j] = r;
}

__global__ void k_packc(const float* __restrict__ whh, const float* __restrict__ wih,
                        uint16_t* __restrict__ wbc) {
    int col = blockIdx.x;
    for (int k = threadIdx.x; k < 288; k += 256) {
        float v = (k < 256) ? whh[(size_t)col * 256 + k] : wih[(size_t)col * 32 + (k - 256)];
        wbc[(size_t)col * 288 + k] = f2bf(v);
    }
}

// ---------------------------------------------------------------------------
// K1: teacher-forced recurrence. 128 blocks x 256 threads.
// ---------------------------------------------------------------------------
__global__ __launch_bounds__(256) void k_rnn_tf(
    const float* __restrict__ y, const uint2* __restrict__ whh2,
    const uint2* __restrict__ wih2, const float* __restrict__ cb,
    uint16_t* __restrict__ Zg, float* __restrict__ zfinal)
{
    __shared__ alignas(16) float zl[LAT];
    __shared__ alignas(16) float ys[OBS];
    int j = threadIdx.x, b = blockIdx.x;
    zl[j] = 0.f;
    __syncthreads();
    const float4* z4 = (const float4*)zl;
    const float4* y4 = (const float4*)ys;
    for (int t = 0; t < TTF; t++) {
        if (j < OBS) ys[j] = y[(size_t)b * (TTF * OBS) + t * OBS + j];
        Zg[((size_t)b * TTF + t) * LAT + j] = f2bf(zl[j]);
        __syncthreads();
        float acc = cb[j];
        #pragma unroll 8
        for (int k4 = 0; k4 < 64; k4++) {
            uint2 wv = whh2[k4 * 256 + j];
            float4 zq = z4[k4];
            acc += bflo(wv.x) * zq.x + bfhi(wv.x) * zq.y
                 + bflo(wv.y) * zq.z + bfhi(wv.y) * zq.w;
        }
        #pragma unroll
        for (int k4 = 0; k4 < 8; k4++) {
            uint2 wv = wih2[k4 * 256 + j];
            float4 yq = y4[k4];
            acc += bflo(wv.x) * yq.x + bfhi(wv.x) * yq.y
                 + bflo(wv.y) * yq.z + bfhi(wv.y) * yq.w;
        }
        __syncthreads();
        zl[j] = fast_tanh(acc);
    }
    __syncthreads();
    zfinal[(size_t)b * LAT + j] = zl[j];
}

// ---------------------------------------------------------------------------
// K2: bulk psi over all 32768 phase-1 states. 1024 blocks x 32 rows, 512 thr.
// ---------------------------------------------------------------------------
__global__ __launch_bounds__(512) void k_psi_bulk(
    const uint16_t* __restrict__ Zg,
    const uint16_t* __restrict__ wb1, const uint16_t* __restrict__ wb2,
    const uint16_t* __restrict__ wb3, const uint16_t* __restrict__ wb4,
    const uint16_t* __restrict__ wb5,
    const float* __restrict__ b1, const float* __restrict__ b2,
    const float* __restrict__ b3, const float* __restrict__ b4,
    const float* __restrict__ b5, float* __restrict__ out)
{
    __shared__ uint16_t hbuf[32 * 1024];   // 64 KB, swizzled
    int tid = threadIdx.x;
    int w = tid >> 6, L = tid & 63, lm = L & 15, q = L >> 4;
    int rb = blockIdx.x * 32;
    int colbase = w * 128;
    floatx4 acc[2][8];
    const floatx4 zero = {0.f, 0.f, 0.f, 0.f};

    #pragma unroll
    for (int mt = 0; mt < 2; mt++)
        #pragma unroll
        for (int nt = 0; nt < 8; nt++) acc[mt][nt] = zero;
    for (int kc = 0; kc < 8; kc++) {
        short8 a0 = *(const short8*)(Zg + (size_t)(rb + lm) * LAT + kc * 32 + q * 8);
        short8 a1 = *(const short8*)(Zg + (size_t)(rb + 16 + lm) * LAT + kc * 32 + q * 8);
        #pragma unroll
        for (int nt = 0; nt < 8; nt++) {
            int n = colbase + nt * 16 + lm;
            short8 bf = *(const short8*)(wb1 + (size_t)n * LAT + kc * 32 + q * 8);
            acc[0][nt] = __builtin_amdgcn_mfma_f32_16x16x32_bf16(a0, bf, acc[0][nt], 0, 0, 0);
            acc[1][nt] = __builtin_amdgcn_mfma_f32_16x16x32_bf16(a1, bf, acc[1][nt], 0, 0, 0);
        }
    }
    #pragma unroll
    for (int mt = 0; mt < 2; mt++)
        #pragma unroll
        for (int nt = 0; nt < 8; nt++) {
            int col = colbase + nt * 16 + lm;
            float bias = b1[col];
            #pragma unroll
            for (int i = 0; i < 4; i++) {
                int row = mt * 16 + q * 4 + i;
                hbuf[hswz(row, col)] = f2bf(fmaxf(acc[mt][nt][i] + bias, 0.f));
            }
        }
    __syncthreads();

    const uint16_t* wbs[3] = {wb2, wb3, wb4};
    const float*    bbs[3] = {b2, b3, b4};
    for (int ll = 0; ll < 3; ll++) {
        const uint16_t* wb = wbs[ll];
        const float* bb = bbs[ll];
        #pragma unroll
        for (int mt = 0; mt < 2; mt++)
            #pragma unroll
            for (int nt = 0; nt < 8; nt++) acc[mt][nt] = zero;
        for (int kc = 0; kc < 32; kc++) {
            int g = ((kc * 4 + q) ^ (lm & 7)) << 3;
            short8 a0 = *(const short8*)(hbuf + lm * 1024 + g);
            short8 a1 = *(const short8*)(hbuf + (16 + lm) * 1024 + g);
            #pragma unroll
            for (int nt = 0; nt < 8; nt++) {
                int n = colbase + nt * 16 + lm;
                short8 bf = *(const short8*)(wb + (size_t)n * HID + kc * 32 + q * 8);
                acc[0][nt] = __builtin_amdgcn_mfma_f32_16x16x32_bf16(a0, bf, acc[0][nt], 0, 0, 0);
                acc[1][nt] = __builtin_amdgcn_mfma_f32_16x16x32_bf16(a1, bf, acc[1][nt], 0, 0, 0);
            }
        }
        __syncthreads();
        #pragma unroll
        for (int mt = 0; mt < 2; mt++)
            #pragma unroll
            for (int nt = 0; nt < 8; nt++) {
                int col = colbase + nt * 16 + lm;
                float bias = bb[col];
                #pragma unroll
                for (int i = 0; i < 4; i++) {
                    int row = mt * 16 + q * 4 + i;
                    hbuf[hswz(row, col)] = f2bf(fmaxf(acc[mt][nt][i] + bias, 0.f));
                }
            }
        __syncthreads();
    }

    if (w < 4) {
        int mt = w >> 1;
        int nb = (w & 1) * 16;
        floatx4 a5 = zero;
        for (int kc = 0; kc < 32; kc++) {
            int g = ((kc * 4 + q) ^ (lm & 7)) << 3;
            short8 a = *(const short8*)(hbuf + (mt * 16 + lm) * 1024 + g);
            short8 bf = *(const short8*)(wb5 + (size_t)(nb + lm) * HID + kc * 32 + q * 8);
            a5 = __builtin_amdgcn_mfma_f32_16x16x32_bf16(a, bf, a5, 0, 0, 0);
        }
        int col = nb + lm;
        float bias = b5[col];
        #pragma unroll
        for (int i = 0; i < 4; i++) {
            int row = mt * 16 + q * 4 + i;
            int r = rb + row;
            int bb_ = r >> 8, tt = r & 255;
            out[(size_t)bb_ * (HOR * OBS) + tt * OBS + col] = a5[i] + bias;
        }
    }
}

// ---------------------------------------------------------------------------
// K3 v15: persistent AR. Hops 1-3 as R14 (ARRIVE/CCZ/WAIT + 32KB stage).
// Hop 4: L4 slice -> distributed L5 partial (1 MFMA/wave) -> f32 atomic
// reduction at MALL (512 words) -> arrive -> CCZ -> wait -> 2KB readback.
// Tail: bias+out+yscr from reduced yh, cell finish, z' -> LDS parity.
// ---------------------------------------------------------------------------
__global__ __launch_bounds__(ARTHREADS) void k_ar2(
    const float* __restrict__ zfinal,
    const uint16_t* __restrict__ wb1, const uint16_t* __restrict__ wb2,
    const uint16_t* __restrict__ wb3, const uint16_t* __restrict__ wb4,
    const uint16_t* __restrict__ wb5, const uint16_t* __restrict__ wbc,
    const float* __restrict__ b1g, const float* __restrict__ b2g,
    const float* __restrict__ b3g, const float* __restrict__ b4g,
    const float* __restrict__ b5g, const float* __restrict__ cb,
    uint16_t* __restrict__ hb_all, unsigned* __restrict__ ctr_all,
    float* __restrict__ yh_all, float* __restrict__ out)
{
    __shared__ alignas(16) uint16_t hstg[16 * 1024];   // 32 KB staged h tile
    __shared__ alignas(16) uint16_t zst[2 * 16 * 256]; // 16 KB z parity buffers
    __shared__ alignas(16) uint16_t yscr[16 * 32];     // 1 KB
    __shared__ alignas(16) uint16_t hsl[16 * 32];      // 1 KB slice transpose
    __shared__ alignas(16) float yhf[512];             // 2 KB reduced yh

    const int tid = threadIdx.x;
    const int g = blockIdx.x >> 5, m = blockIdx.x & 31;   // member m -> XCD m%8
    const int w = tid >> 6, L = tid & 63, lm = L & 15, q = L >> 4, lm7 = lm & 7;
    const int colbase = m * 32;
    const int cl = w * 16 + lm;
    const int rb = g * 16;
    uint16_t* hb = hb_all + (size_t)g * (8 * 16 * HID);   // 2 parity x 4 slots
    unsigned* ctr = ctr_all + g * 128;
    float* yhg = yh_all + g * 1024;                        // 2 parity x 512 f32
    const floatx4 zero = {0.f, 0.f, 0.f, 0.f};

    // loop-invariant bias loads, hoisted out of the t-loop
    const float b1v = b1g[colbase + cl];
    const float b2v = b2g[colbase + cl];
    const float b3v = b3g[colbase + cl];
    const float b4v = b4g[colbase + cl];
    const float b5v = b5g[cl];
    float cbv[8];
    #pragma unroll
    for (int ct = 0; ct < 8; ct++) cbv[ct] = cb[w * 128 + ct * 16 + lm];

    // initial z: local LDS only (every member keeps its own copy), swizzled
    for (int idx = tid; idx < 16 * 256; idx += ARTHREADS) {
        int r = idx >> 8, c = idx & 255;
        zst[zswz(r, c)] = f2bf(zfinal[(size_t)(rb + r) * LAT + c]);
    }
    __syncthreads();

    // ARRIVE: wave0 publishes slice, drains its stores, lane0 RMWs counter.
    #define HOP_ARRIVE(DST) do {                                             \
        __syncthreads();                                                     \
        if (tid < 64) {                                                      \
            int row_ = tid >> 2, gr_ = tid & 3;                              \
            floatx4 vv_ = *(const floatx4*)((const char*)hsl + tid * 16);    \
            int gsw_ = (m * 4 + gr_) ^ (row_ & 7);                           \
            st16_mall((char*)(DST) + row_ * 2048 + gsw_ * 16, vv_);          \
            asm volatile("s_waitcnt vmcnt(0)" ::: "memory");                 \
            if (tid == 0)                                                    \
                __hip_atomic_fetch_add(ctr, 1u, __ATOMIC_RELAXED,            \
                                       __HIP_MEMORY_SCOPE_AGENT);            \
        }                                                                    \
    } while (0)

    // WAIT: tid0 spins on the group counter, then one block barrier.
    #define HOP_WAIT(TGT) do {                                               \
        if (tid == 0) {                                                      \
            while (__hip_atomic_load(ctr, __ATOMIC_RELAXED,                  \
                                     __HIP_MEMORY_SCOPE_AGENT) < (TGT)) {}   \
        }                                                                    \
        __syncthreads();                                                     \
    } while (0)

    // cell z-part chunk: kc in [K0,K1), accumulated into cc[8]
    #define CCZ(K0, K1) do {                                                 \
        _Pragma("unroll")                                                    \
        for (int ct = 0; ct < 8; ct++) {                                     \
            const uint16_t* bb2_ = wbc + (size_t)(w * 128 + ct * 16 + lm) * 288 + q * 8; \
            _Pragma("unroll")                                                \
            for (int kc = (K0); kc < (K1); kc++) {                           \
                int gz_ = (kc * 4 + q) ^ lm7;                                \
                short8 a_ = *(const short8*)(zcur + lm * 256 + gz_ * 8);     \
                short8 b_ = *(const short8*)(bb2_ + kc * 32);                \
                cc[ct] = __builtin_amdgcn_mfma_f32_16x16x32_bf16(a_, b_, cc[ct], 0, 0, 0); \
            }                                                                \
        }                                                                    \
    } while (0)

    #define MID_COMPUTE(WB, BV) do {                                         \
        floatx4 acc_ = zero;                                                 \
        const uint16_t* bb_ = WB + (size_t)(colbase + cl) * HID + q * 8;     \
        _Pragma("unroll 8")                                                  \
        for (int kc = 0; kc < 32; kc++) {                                    \
            int gh = (kc * 4 + q) ^ lm7;                                     \
            short8 a_ = *(const short8*)(hstg + lm * 1024 + gh * 8);         \
            short8 b_ = *(const short8*)(bb_ + kc * 32);                     \
            acc_ = __builtin_amdgcn_mfma_f32_16x16x32_bf16(a_, b_, acc_, 0, 0, 0); \
        }                                                                    \
        _Pragma("unroll")                                                    \
        for (int i = 0; i < 4; i++)                                          \
            hsl[(q * 4 + i) * 32 + cl] = f2bf(fmaxf(acc_[i] + (BV), 0.f));   \
    } while (0)

    unsigned tgt = 0;
    #pragma unroll 1
    for (int t = 0; t < HOR - TTF; t++) {
        uint16_t* zcur = zst + (t & 1) * (16 * 256);
        uint16_t* znx  = zst + ((t + 1) & 1) * (16 * 256);
        uint16_t* hp = hb + (t & 1) * (4 * 16 * HID);     // step-parity tiles
        uint16_t* h1 = hp;
        uint16_t* h2 = hp + 16 * HID;
        uint16_t* h3 = hp + 2 * 16 * HID;
        float* ya  = yhg + (t & 1) * 512;                 // this step's reducer
        float* yaz = yhg + ((t + 1) & 1) * 512;           // zero for step t+2

        floatx4 cc[8];
        #pragma unroll
        for (int ct = 0; ct < 8; ct++) cc[ct] = zero;

        // ---- L1 slice from LDS z (local) ----
        {
            floatx4 acc = zero;
            const uint16_t* bb = wb1 + (size_t)(colbase + cl) * LAT + q * 8;
            #pragma unroll
            for (int kc = 0; kc < 8; kc++) {
                int gz = (kc * 4 + q) ^ lm7;
                short8 a = *(const short8*)(zcur + lm * 256 + gz * 8);
                short8 b = *(const short8*)(bb + kc * 32);
                acc = __builtin_amdgcn_mfma_f32_16x16x32_bf16(a, b, acc, 0, 0, 0);
            }
            #pragma unroll
            for (int i = 0; i < 4; i++)
                hsl[(q * 4 + i) * 32 + cl] = f2bf(fmaxf(acc[i] + b1v, 0.f));
        }
        HOP_ARRIVE(h1); tgt += MEMBERS;
        CCZ(0, 2);
        HOP_WAIT(tgt);
        // zero next-parity yh accumulator (wave0 only: hop-2 ARRIVE's drain
        // + the barrier chain order it before step t+2's atomic adds; all
        // members have read this buffer -- they arrived at this barrier)
        if (tid < 64) {
            st16_mall((char*)yaz + tid * 32, zero);
            st16_mall((char*)yaz + tid * 32 + 16, zero);
        }
        stage_h(h1, hstg, w, L);
        __syncthreads();

        MID_COMPUTE(wb2, b2v);
        HOP_ARRIVE(h2); tgt += MEMBERS;
        CCZ(2, 4);
        HOP_WAIT(tgt);
        stage_h(h2, hstg, w, L);
        __syncthreads();

        MID_COMPUTE(wb3, b3v);
        HOP_ARRIVE(h3); tgt += MEMBERS;
        CCZ(4, 6);
        HOP_WAIT(tgt);
        stage_h(h3, hstg, w, L);
        __syncthreads();

        // ---- hop 4: L4 slice -> distributed L5 partial -> MALL reduction ----
        MID_COMPUTE(wb4, b4v);
        __syncthreads();
        {
            // L5 partial from own h4 slice (K=32): wave w -> out cols w*16..
            short8 a = *(const short8*)(hsl + lm * 32 + q * 8);
            short8 b = *(const short8*)(wb5 + (size_t)(w * 16 + lm) * HID + m * 32 + q * 8);
            floatx4 p = __builtin_amdgcn_mfma_f32_16x16x32_bf16(a, b, zero, 0, 0, 0);
            #pragma unroll
            for (int i = 0; i < 4; i++)
                __hip_atomic_fetch_add(ya + (q * 4 + i) * 32 + w * 16 + lm, p[i],
                                       __ATOMIC_RELAXED, __HIP_MEMORY_SCOPE_AGENT);
            asm volatile("s_waitcnt vmcnt(0)" ::: "memory");
        }
        __syncthreads();
        if (tid == 0)
            __hip_atomic_fetch_add(ctr, 1u, __ATOMIC_RELAXED, __HIP_MEMORY_SCOPE_AGENT);
        tgt += MEMBERS;
        CCZ(6, 8);
        HOP_WAIT(tgt);
        // 2KB readback of the reduced yh (MALL-coherent DMA)
        gl_lds16((const char*)ya + w * 1024 + L * 16, (char*)yhf + w * 1024 + L * 16);
        __syncthreads();

        // ---- tail: bias + out + yscr from reduced yh ----
        {
            float vout[4];
            #pragma unroll
            for (int i = 0; i < 4; i++) {
                float v = yhf[(q * 4 + i) * 32 + cl] + b5v;
                vout[i] = v;
                yscr[(q * 4 + i) * 32 + cl] = f2bf(v);
            }
            if (m == 0) {
                #pragma unroll
                for (int i = 0; i < 4; i++)
                    out[(size_t)(rb + q * 4 + i) * (HOR * OBS) + (TTF + t) * OBS + cl] = vout[i];
            }
        }
        __syncthreads();
        // cell finish: add the yh term (kc=8) to cc[], tanh, write z'
        {
            short8 ay = *(const short8*)(yscr + lm * 32 + q * 8);
            #pragma unroll
            for (int ct = 0; ct < 8; ct++) {
                int ccol = w * 128 + ct * 16 + lm;
                const uint16_t* bb2 = wbc + (size_t)ccol * 288 + q * 8;
                short8 b = *(const short8*)(bb2 + 8 * 32);
                floatx4 v = __builtin_amdgcn_mfma_f32_16x16x32_bf16(ay, b, cc[ct], 0, 0, 0);
                #pragma unroll
                for (int i = 0; i < 4; i++)
                    znx[zswz(q * 4 + i, ccol)] = f2bf(fast_tanh(v[i] + cbv[ct]));
            }
        }
        __syncthreads();
    }
    #undef MID_COMPUTE
    #undef CCZ
    #undef HOP_WAIT
    #undef HOP_ARRIVE
}

// ---------------------------------------------------------------------------
extern "C" void kernel_launch(void* const* d_in, const int* in_sizes, int n_in,
                              void* d_out, int out_size, void* d_ws, size_t ws_size,
                              hipStream_t stream) {
    (void)in_sizes; (void)n_in; (void)out_size; (void)ws_size;
    const float* y    = (const float*)d_in[0];
    const float* W_ih = (const float*)d_in[2];
    const float* W_hh = (const float*)d_in[3];
    const float* b_ih = (const float*)d_in[4];
    const float* b_hh = (const float*)d_in[5];
    const float* W1   = (const float*)d_in[6];
    const float* b1   = (const float*)d_in[7];
    const float* W2   = (const float*)d_in[8];
    const float* b2   = (const float*)d_in[9];
    const float* W3   = (const float*)d_in[10];
    const float* b3   = (const float*)d_in[11];
    const float* W4   = (const float*)d_in[12];
    const float* b4   = (const float*)d_in[13];
    const float* W5   = (const float*)d_in[14];
    const float* b5   = (const float*)d_in[15];
    float* out = (float*)d_out;
    char* ws = (char*)d_ws;

    uint16_t* WB1  = (uint16_t*)(ws + OFF_WB1);
    uint16_t* WB2  = (uint16_t*)(ws + OFF_WB2);
    uint16_t* WB3  = (uint16_t*)(ws + OFF_WB3);
    uint16_t* WB4  = (uint16_t*)(ws + OFF_WB4);
    uint16_t* WB5  = (uint16_t*)(ws + OFF_WB5);
    float*    CB   = (float*)(ws + OFF_CB);
    uint2*    WHH2 = (uint2*)(ws + OFF_WHH2);
    uint2*    WIH2 = (uint2*)(ws + OFF_WIH2);
    float*    ZF   = (float*)(ws + OFF_ZF);
    uint16_t* Zbuf = (uint16_t*)(ws + OFF_Z);
    uint16_t* WBC  = (uint16_t*)(ws + OFF_WBC);
    uint16_t* HB   = (uint16_t*)(ws + OFF_HB);
    unsigned* CTR  = (unsigned*)(ws + OFF_CTR);
    float*    YH   = (float*)(ws + OFF_YH);

    k_cvt<<<(HID*LAT + 255) / 256, 256, 0, stream>>>(W1, WB1, HID * LAT);
    k_cvt<<<(HID*HID + 255) / 256, 256, 0, stream>>>(W2, WB2, HID * HID);
    k_cvt<<<(HID*HID + 255) / 256, 256, 0, stream>>>(W3, WB3, HID * HID);
    k_cvt<<<(HID*HID + 255) / 256, 256, 0, stream>>>(W4, WB4, HID * HID);
    k_cvt<<<(OBS*HID + 255) / 256, 256, 0, stream>>>(W5, WB5, OBS * HID);
    k_cb<<<1, 256, 0, stream>>>(b_ih, b_hh, CB);
    k_pack<<<64, 256, 0, stream>>>(W_hh, WHH2, LAT);
    k_pack<<<8, 256, 0, stream>>>(W_ih, WIH2, OBS);
    k_packc<<<256, 256, 0, stream>>>(W_hh, W_ih, WBC);
    hipMemsetAsync(CTR, 0, GROUPS * 512 + GROUPS * 4096, stream);

    k_rnn_tf<<<BATCH, 256, 0, stream>>>(y, WHH2, WIH2, CB, Zbuf, ZF);

    k_psi_bulk<<<(BATCH * TTF) / 32, 512, 0, stream>>>(
        Zbuf, WB1, WB2, WB3, WB4, WB5, b1, b2, b3, b4, b5, out);

    // Cooperative launch preferred (guaranteed co-residency); on ANY error
    // fall back to a plain launch — 256 blocks at 1+/CU are co-resident.
    void* args[] = {
        (void*)&ZF, (void*)&WB1, (void*)&WB2, (void*)&WB3, (void*)&WB4,
        (void*)&WB5, (void*)&WBC, (void*)&b1, (void*)&b2, (void*)&b3,
        (void*)&b4, (void*)&b5, (void*)&CB, (void*)&HB, (void*)&CTR,
        (void*)&YH, (void*)&out
    };
    hipError_t ce = hipLaunchCooperativeKernel((const void*)k_ar2,
                                               dim3(ARBLOCKS), dim3(ARTHREADS),
                                               args, 0, stream);
    if (ce != hipSuccess) {
        (void)hipGetLastError();   // clear sticky error
        k_ar2<<<dim3(ARBLOCKS), dim3(ARTHREADS), 0, stream>>>(
            ZF, WB1, WB2, WB3, WB4, WB5, WBC, b1, b2, b3, b4, b5, CB,
            HB, CTR, YH, out);
    }
}

// Round 8
// 7925.266 us; speedup vs baseline: 1.0835x; 1.0835x over previous
//
#include <hip/hip_runtime.h>
#include <stdint.h>

// ---------------------------------------------------------------------------
// RNN rollout. Phase 1: teacher-forced recurrence + bulk psi. Phase 2:
// persistent AR kernel, 8 groups x 32 members, member m -> XCD m%8 (weight
// slices L2-resident, R6/R8). Failed variants (do not retry): co-located
// groups (R9), in-grid psi fusion (R11), redundant full-L1 (R12), epoch-flag
// exchange (R13), MALL-atomic L5 reduction (R15: same-address atomic
// serialization, WRITE_SIZE 274K->602K, steady 4800->6731).
// R14 AR structure (4800us steady, best known) restored VERBATIM:
//   ARRIVE (publish 64x16B sc0|sc1 + drain + lane0 RMW) / overlap (cell
//   z-part, CCZ) / WAIT (tid0 spin + 1 syncthreads); tail = stage h4 + L5
//   redundant + cell finish; step-parity h tiles.
// R16 change: k_psi_bulk (~1.1ms, 208 TF, weight-re-read-bound: 32-row
// blocks stream 2MB/layer each => ~6GB MALL) replaced by chunked per-layer
// GEMMs:
//   - col-slice c = blockIdx&7 -> all row-tiles of slice c land on XCD c
//     (round-robin dispatch), so each 256KB weight slice is read ~once per
//     XCD and stays L2-hot; activations ping-pong in two 16MB MALL-resident
//     buffers; 4 row-chunks x 5 layers = 20 launches.
//   - fragment addressing + K-chain order copied from psi_bulk verbatim =>
//     bitwise-identical results.
//   - ws_size guard: if workspace < needed, fall back to the unchanged
//     k_psi_bulk (no-regression safety).
// Sizes fixed: B=128, T=256, HOR=512, OBS=32, LAT=256, HID=1024.
// ---------------------------------------------------------------------------

#define BATCH 128
#define TTF   256
#define HOR   512
#define OBS   32
#define LAT   256
#define HID   1024

#define GROUPS  8
#define MEMBERS 32
#define ARBLOCKS (GROUPS * MEMBERS)
#define ARTHREADS 128

#define PSI_CHUNK 8192                 // rows per psi chunk (4 chunks total)

typedef __attribute__((ext_vector_type(8))) short short8;
typedef __attribute__((ext_vector_type(4))) float floatx4;

// ---- workspace layout (bytes) ----
#define OFF_WB1   ((size_t)0)                          // 1024x256 bf16 ([col][k])
#define OFF_WB2   (OFF_WB1 + (size_t)HID*LAT*2)        // 1024x1024 bf16
#define OFF_WB3   (OFF_WB2 + (size_t)HID*HID*2)
#define OFF_WB4   (OFF_WB3 + (size_t)HID*HID*2)
#define OFF_WB5   (OFF_WB4 + (size_t)HID*HID*2)        // 32x1024 bf16
#define OFF_CB    (OFF_WB5 + (size_t)OBS*HID*2)        // 256 f32 (b_ih+b_hh)
#define OFF_WHH2  (OFF_CB + (size_t)LAT*4)             // 64x256 uint2 packed W_hh^T
#define OFF_WIH2  (OFF_WHH2 + (size_t)64*256*8)        // 8x256 uint2 packed W_ih^T
#define OFF_ZF    (OFF_WIH2 + (size_t)8*256*8)         // 128x256 f32
#define OFF_Z     (OFF_ZF + (size_t)BATCH*LAT*4)       // 32768x256 bf16
#define OFF_WBC   (OFF_Z + (size_t)BATCH*TTF*LAT*2)    // 256x288 bf16 cell matrix
#define OFF_HB    (OFF_WBC + (size_t)LAT*288*2)        // 8 x 2par x 4 x 16x1024 bf16
#define OFF_CTR   (OFF_HB + (size_t)GROUPS*8*16*HID*2) // 8 x 512B counters
#define OFF_HA    (OFF_CTR + (size_t)GROUPS*512)       // 8192x1024 bf16 (16MB)
#define OFF_HBF   (OFF_HA + (size_t)PSI_CHUNK*HID*2)   // 8192x1024 bf16 (16MB)
#define OFF_END   (OFF_HBF + (size_t)PSI_CHUNK*HID*2)

__device__ __forceinline__ uint16_t f2bf(float f) {
    uint32_t u = __float_as_uint(f);
    u += 0x7fffu + ((u >> 16) & 1u);   // RNE
    return (uint16_t)(u >> 16);
}
__device__ __forceinline__ float bflo(uint32_t u) { return __uint_as_float(u << 16); }
__device__ __forceinline__ float bfhi(uint32_t u) { return __uint_as_float(u & 0xffff0000u); }

__device__ __forceinline__ float fast_tanh(float x) {
    float ax = fabsf(x);
    float e  = __expf(-2.f * ax);
    float r  = (1.f - e) / (1.f + e);
    return copysignf(r, x);
}

// XOR-granule swizzles (16B granule index ^ low bits of row). Producers store
// swizzled; the verbatim DMA lands swizzled in LDS; readers XOR back.
__device__ __forceinline__ int hswz(int row, int col) {   // h: stride 1024
    return row * 1024 + ((((col >> 3) ^ (row & 7)) << 3) | (col & 7));
}
__device__ __forceinline__ int zswz(int row, int col) {   // z: stride 256
    return row * 256 + ((((col >> 3) ^ (row & 7)) << 3) | (col & 7));
}

// 16B MALL-coherent store (sc0|sc1 write-through, proven R9/R10).
__device__ __forceinline__ void st16_mall(void* p, floatx4 v) {
    asm volatile("global_store_dwordx4 %0, %1, off sc0 sc1"
                 :: "v"(p), "v"(v) : "memory");
}

// async DMA global->LDS, 16 B/lane, aux=0x11 (CPol SC0|SC1): reads at MALL
// (coherent with the sc0|sc1 writers), does not allocate into L1/L2.
typedef const __attribute__((address_space(1))) void* gas_t;
typedef __attribute__((address_space(3))) void* las_t;
__device__ __forceinline__ void gl_lds16(const void* g, void* l) {
    __builtin_amdgcn_global_load_lds((gas_t)g, (las_t)l, 16, 0, 0x11);
}

// 32 KB h tile MALL -> LDS: per wave 16 issues x 1 KB, all in flight.
__device__ __forceinline__ void stage_h(const uint16_t* src, uint16_t* dst,
                                        int w, int L) {
    const char* gp = (const char*)src + w * 16384 + L * 16;
    char* lp = (char*)dst + w * 16384;
    #pragma unroll
    for (int i = 0; i < 16; i++)
        gl_lds16(gp + i * 1024, lp + i * 1024);
}

// ---------------------------------------------------------------------------
// K0 helpers
// ---------------------------------------------------------------------------
__global__ void k_cvt(const float* __restrict__ s, uint16_t* __restrict__ d, int n) {
    int i = blockIdx.x * 256 + threadIdx.x;
    if (i < n) d[i] = f2bf(s[i]);
}

__global__ void k_cb(const float* __restrict__ a, const float* __restrict__ b,
                     float* __restrict__ c) {
    int j = threadIdx.x;
    c[j] = a[j] + b[j];
}

__global__ void k_pack(const float* __restrict__ w, uint2* __restrict__ dst, int klen) {
    int k4 = blockIdx.x, j = threadIdx.x;
    int k = k4 * 4;
    uint32_t a = f2bf(w[(size_t)j * klen + k + 0]);
    uint32_t b = f2bf(w[(size_t)j * klen + k + 1]);
    uint32_t c = f2bf(w[(size_t)j * klen + k + 2]);
    uint32_t d = f2bf(w[(size_t)j * klen + k + 3]);
    uint2 r; r.x = a | (b << 16); r.y = c | (d << 16);
    dst[k4 * 256 + j] = r;
}

__global__ void k_packc(const float* __restrict__ whh, const float* __restrict__ wih,
                        uint16_t* __restrict__ wbc) {
    int col = blockIdx.x;
    for (int k = threadIdx.x; k < 288; k += 256) {
        float v = (k < 256) ? whh[(size_t)col * 256 + k] : wih[(size_t)col * 32 + (k - 256)];
        wbc[(size_t)col * 288 + k] = f2bf(v);
    }
}

// ---------------------------------------------------------------------------
// K1: teacher-forced recurrence. 128 blocks x 256 threads.
// ---------------------------------------------------------------------------
__global__ __launch_bounds__(256) void k_rnn_tf(
    const float* __restrict__ y, const uint2* __restrict__ whh2,
    const uint2* __restrict__ wih2, const float* __restrict__ cb,
    uint16_t* __restrict__ Zg, float* __restrict__ zfinal)
{
    __shared__ alignas(16) float zl[LAT];
    __shared__ alignas(16) float ys[OBS];
    int j = threadIdx.x, b = blockIdx.x;
    zl[j] = 0.f;
    __syncthreads();
    const float4* z4 = (const float4*)zl;
    const float4* y4 = (const float4*)ys;
    for (int t = 0; t < TTF; t++) {
        if (j < OBS) ys[j] = y[(size_t)b * (TTF * OBS) + t * OBS + j];
        Zg[((size_t)b * TTF + t) * LAT + j] = f2bf(zl[j]);
        __syncthreads();
        float acc = cb[j];
        #pragma unroll 8
        for (int k4 = 0; k4 < 64; k4++) {
            uint2 wv = whh2[k4 * 256 + j];
            float4 zq = z4[k4];
            acc += bflo(wv.x) * zq.x + bfhi(wv.x) * zq.y
                 + bflo(wv.y) * zq.z + bfhi(wv.y) * zq.w;
        }
        #pragma unroll
        for (int k4 = 0; k4 < 8; k4++) {
            uint2 wv = wih2[k4 * 256 + j];
            float4 yq = y4[k4];
            acc += bflo(wv.x) * yq.x + bfhi(wv.x) * yq.y
                 + bflo(wv.y) * yq.z + bfhi(wv.y) * yq.w;
        }
        __syncthreads();
        zl[j] = fast_tanh(acc);
    }
    __syncthreads();
    zfinal[(size_t)b * LAT + j] = zl[j];
}

// ---------------------------------------------------------------------------
// K2 new: chunked per-layer psi GEMMs. c = blockIdx&7 -> XCD c owns the
// 128-col weight slice (L2-hot); 32-row tiles stream from MALL. Fragment
// addressing identical to k_psi_bulk => bitwise-identical results.
// ---------------------------------------------------------------------------
__global__ __launch_bounds__(512) void k_psi_l1(
    const uint16_t* __restrict__ zin,   // [PSI_CHUNK][256] (chunk base)
    const uint16_t* __restrict__ wb,    // [1024][256]
    const float* __restrict__ bias, uint16_t* __restrict__ hout)
{
    const int tid = threadIdx.x;
    const int w = tid >> 6, L = tid & 63, lm = L & 15, q = L >> 4;
    const int c = blockIdx.x & 7, rt = blockIdx.x >> 3;
    const int rb = rt * 32;
    const int rf = w & 1, cp = w >> 1;
    const int cbase = c * 128 + cp * 32;
    floatx4 acc0 = {0.f,0.f,0.f,0.f}, acc1 = {0.f,0.f,0.f,0.f};
    const uint16_t* ap  = zin + (size_t)(rb + rf * 16 + lm) * LAT + q * 8;
    const uint16_t* bp0 = wb + (size_t)(cbase + lm) * LAT + q * 8;
    const uint16_t* bp1 = wb + (size_t)(cbase + 16 + lm) * LAT + q * 8;
    #pragma unroll
    for (int kc = 0; kc < 8; kc++) {
        short8 a  = *(const short8*)(ap  + kc * 32);
        short8 b0 = *(const short8*)(bp0 + kc * 32);
        short8 b1 = *(const short8*)(bp1 + kc * 32);
        acc0 = __builtin_amdgcn_mfma_f32_16x16x32_bf16(a, b0, acc0, 0, 0, 0);
        acc1 = __builtin_amdgcn_mfma_f32_16x16x32_bf16(a, b1, acc1, 0, 0, 0);
    }
    float bv0 = bias[cbase + lm], bv1 = bias[cbase + 16 + lm];
    #pragma unroll
    for (int i = 0; i < 4; i++) {
        int row = rb + rf * 16 + q * 4 + i;
        hout[(size_t)row * HID + cbase + lm]      = f2bf(fmaxf(acc0[i] + bv0, 0.f));
        hout[(size_t)row * HID + cbase + 16 + lm] = f2bf(fmaxf(acc1[i] + bv1, 0.f));
    }
}

__global__ __launch_bounds__(512) void k_psi_mid(
    const uint16_t* __restrict__ hin,   // [PSI_CHUNK][1024]
    const uint16_t* __restrict__ wb,    // [1024][1024]
    const float* __restrict__ bias, uint16_t* __restrict__ hout)
{
    const int tid = threadIdx.x;
    const int w = tid >> 6, L = tid & 63, lm = L & 15, q = L >> 4;
    const int c = blockIdx.x & 7, rt = blockIdx.x >> 3;
    const int rb = rt * 32;
    const int rf = w & 1, cp = w >> 1;
    const int cbase = c * 128 + cp * 32;
    floatx4 acc0 = {0.f,0.f,0.f,0.f}, acc1 = {0.f,0.f,0.f,0.f};
    const uint16_t* ap  = hin + (size_t)(rb + rf * 16 + lm) * HID + q * 8;
    const uint16_t* bp0 = wb + (size_t)(cbase + lm) * HID + q * 8;
    const uint16_t* bp1 = wb + (size_t)(cbase + 16 + lm) * HID + q * 8;
    #pragma unroll 8
    for (int kc = 0; kc < 32; kc++) {
        short8 a  = *(const short8*)(ap  + kc * 32);
        short8 b0 = *(const short8*)(bp0 + kc * 32);
        short8 b1 = *(const short8*)(bp1 + kc * 32);
        acc0 = __builtin_amdgcn_mfma_f32_16x16x32_bf16(a, b0, acc0, 0, 0, 0);
        acc1 = __builtin_amdgcn_mfma_f32_16x16x32_bf16(a, b1, acc1, 0, 0, 0);
    }
    float bv0 = bias[cbase + lm], bv1 = bias[cbase + 16 + lm];
    #pragma unroll
    for (int i = 0; i < 4; i++) {
        int row = rb + rf * 16 + q * 4 + i;
        hout[(size_t)row * HID + cbase + lm]      = f2bf(fmaxf(acc0[i] + bv0, 0.f));
        hout[(size_t)row * HID + cbase + 16 + lm] = f2bf(fmaxf(acc1[i] + bv1, 0.f));
    }
}

__global__ __launch_bounds__(128) void k_psi_l5(
    const uint16_t* __restrict__ hin,   // [PSI_CHUNK][1024]
    const uint16_t* __restrict__ wb5,   // [32][1024]
    const float* __restrict__ bias, float* __restrict__ out, int row0)
{
    const int tid = threadIdx.x;
    const int w = tid >> 6, L = tid & 63, lm = L & 15, q = L >> 4;
    const int rt = blockIdx.x;
    const int rb = rt * 32;
    const int rf = w;                    // 2 waves: row frags 0/1
    floatx4 acc0 = {0.f,0.f,0.f,0.f}, acc1 = {0.f,0.f,0.f,0.f};
    const uint16_t* ap  = hin + (size_t)(rb + rf * 16 + lm) * HID + q * 8;
    const uint16_t* bp0 = wb5 + (size_t)lm * HID + q * 8;
    const uint16_t* bp1 = wb5 + (size_t)(16 + lm) * HID + q * 8;
    #pragma unroll 8
    for (int kc = 0; kc < 32; kc++) {
        short8 a  = *(const short8*)(ap  + kc * 32);
        short8 b0 = *(const short8*)(bp0 + kc * 32);
        short8 b1 = *(const short8*)(bp1 + kc * 32);
        acc0 = __builtin_amdgcn_mfma_f32_16x16x32_bf16(a, b0, acc0, 0, 0, 0);
        acc1 = __builtin_amdgcn_mfma_f32_16x16x32_bf16(a, b1, acc1, 0, 0, 0);
    }
    float bv0 = bias[lm], bv1 = bias[16 + lm];
    #pragma unroll
    for (int i = 0; i < 4; i++) {
        int gr = row0 + rb + rf * 16 + q * 4 + i;
        int bb = gr >> 8, tt = gr & 255;
        out[(size_t)bb * (HOR * OBS) + tt * OBS + lm]      = acc0[i] + bv0;
        out[(size_t)bb * (HOR * OBS) + tt * OBS + 16 + lm] = acc1[i] + bv1;
    }
}

// ---------------------------------------------------------------------------
// K2 fallback: bulk psi (R10-proven). Used only when ws_size is too small
// for the HA/HBF ping-pong buffers.
// ---------------------------------------------------------------------------
__global__ __launch_bounds__(512) void k_psi_bulk(
    const uint16_t* __restrict__ Zg,
    const uint16_t* __restrict__ wb1, const uint16_t* __restrict__ wb2,
    const uint16_t* __restrict__ wb3, const uint16_t* __restrict__ wb4,
    const uint16_t* __restrict__ wb5,
    const float* __restrict__ b1, const float* __restrict__ b2,
    const float* __restrict__ b3, const float* __restrict__ b4,
    const float* __restrict__ b5, float* __restrict__ out)
{
    __shared__ uint16_t hbuf[32 * 1024];   // 64 KB, swizzled
    int tid = threadIdx.x;
    int w = tid >> 6, L = tid & 63, lm = L & 15, q = L >> 4;
    int rb = blockIdx.x * 32;
    int colbase = w * 128;
    floatx4 acc[2][8];
    const floatx4 zero = {0.f, 0.f, 0.f, 0.f};

    #pragma unroll
    for (int mt = 0; mt < 2; mt++)
        #pragma unroll
        for (int nt = 0; nt < 8; nt++) acc[mt][nt] = zero;
    for (int kc = 0; kc < 8; kc++) {
        short8 a0 = *(const short8*)(Zg + (size_t)(rb + lm) * LAT + kc * 32 + q * 8);
        short8 a1 = *(const short8*)(Zg + (size_t)(rb + 16 + lm) * LAT + kc * 32 + q * 8);
        #pragma unroll
        for (int nt = 0; nt < 8; nt++) {
            int n = colbase + nt * 16 + lm;
            short8 bf = *(const short8*)(wb1 + (size_t)n * LAT + kc * 32 + q * 8);
            acc[0][nt] = __builtin_amdgcn_mfma_f32_16x16x32_bf16(a0, bf, acc[0][nt], 0, 0, 0);
            acc[1][nt] = __builtin_amdgcn_mfma_f32_16x16x32_bf16(a1, bf, acc[1][nt], 0, 0, 0);
        }
    }
    #pragma unroll
    for (int mt = 0; mt < 2; mt++)
        #pragma unroll
        for (int nt = 0; nt < 8; nt++) {
            int col = colbase + nt * 16 + lm;
            float bias = b1[col];
            #pragma unroll
            for (int i = 0; i < 4; i++) {
                int row = mt * 16 + q * 4 + i;
                hbuf[hswz(row, col)] = f2bf(fmaxf(acc[mt][nt][i] + bias, 0.f));
            }
        }
    __syncthreads();

    const uint16_t* wbs[3] = {wb2, wb3, wb4};
    const float*    bbs[3] = {b2, b3, b4};
    for (int ll = 0; ll < 3; ll++) {
        const uint16_t* wb = wbs[ll];
        const float* bb = bbs[ll];
        #pragma unroll
        for (int mt = 0; mt < 2; mt++)
            #pragma unroll
            for (int nt = 0; nt < 8; nt++) acc[mt][nt] = zero;
        for (int kc = 0; kc < 32; kc++) {
            int g = ((kc * 4 + q) ^ (lm & 7)) << 3;
            short8 a0 = *(const short8*)(hbuf + lm * 1024 + g);
            short8 a1 = *(const short8*)(hbuf + (16 + lm) * 1024 + g);
            #pragma unroll
            for (int nt = 0; nt < 8; nt++) {
                int n = colbase + nt * 16 + lm;
                short8 bf = *(const short8*)(wb + (size_t)n * HID + kc * 32 + q * 8);
                acc[0][nt] = __builtin_amdgcn_mfma_f32_16x16x32_bf16(a0, bf, acc[0][nt], 0, 0, 0);
                acc[1][nt] = __builtin_amdgcn_mfma_f32_16x16x32_bf16(a1, bf, acc[1][nt], 0, 0, 0);
            }
        }
        __syncthreads();
        #pragma unroll
        for (int mt = 0; mt < 2; mt++)
            #pragma unroll
            for (int nt = 0; nt < 8; nt++) {
                int col = colbase + nt * 16 + lm;
                float bias = bb[col];
                #pragma unroll
                for (int i = 0; i < 4; i++) {
                    int row = mt * 16 + q * 4 + i;
                    hbuf[hswz(row, col)] = f2bf(fmaxf(acc[mt][nt][i] + bias, 0.f));
                }
            }
        __syncthreads();
    }

    if (w < 4) {
        int mt = w >> 1;
        int nb = (w & 1) * 16;
        floatx4 a5 = zero;
        for (int kc = 0; kc < 32; kc++) {
            int g = ((kc * 4 + q) ^ (lm & 7)) << 3;
            short8 a = *(const short8*)(hbuf + (mt * 16 + lm) * 1024 + g);
            short8 bf = *(const short8*)(wb5 + (size_t)(nb + lm) * HID + kc * 32 + q * 8);
            a5 = __builtin_amdgcn_mfma_f32_16x16x32_bf16(a, bf, a5, 0, 0, 0);
        }
        int col = nb + lm;
        float bias = b5[col];
        #pragma unroll
        for (int i = 0; i < 4; i++) {
            int row = mt * 16 + q * 4 + i;
            int r = rb + row;
            int bb_ = r >> 8, tt = r & 255;
            out[(size_t)bb_ * (HOR * OBS) + tt * OBS + col] = a5[i] + bias;
        }
    }
}

// ---------------------------------------------------------------------------
// K3 v14 (restored): persistent AR. R10 hop structure, counter barrier split
// into ARRIVE (publish + drain + lane0 RMW) / overlap (cell z-part) / WAIT
// (tid0 spin + one __syncthreads). Tail: stage h4, L5, out, cell finish.
// ---------------------------------------------------------------------------
__global__ __launch_bounds__(ARTHREADS) void k_ar2(
    const float* __restrict__ zfinal,
    const uint16_t* __restrict__ wb1, const uint16_t* __restrict__ wb2,
    const uint16_t* __restrict__ wb3, const uint16_t* __restrict__ wb4,
    const uint16_t* __restrict__ wb5, const uint16_t* __restrict__ wbc,
    const float* __restrict__ b1g, const float* __restrict__ b2g,
    const float* __restrict__ b3g, const float* __restrict__ b4g,
    const float* __restrict__ b5g, const float* __restrict__ cb,
    uint16_t* __restrict__ hb_all, unsigned* __restrict__ ctr_all,
    float* __restrict__ out)
{
    __shared__ alignas(16) uint16_t hstg[16 * 1024];   // 32 KB staged h tile
    __shared__ alignas(16) uint16_t zst[2 * 16 * 256]; // 16 KB z parity buffers
    __shared__ alignas(16) uint16_t yscr[16 * 32];     // 1 KB
    __shared__ alignas(16) uint16_t hsl[16 * 32];      // 1 KB slice transpose

    const int tid = threadIdx.x;
    const int g = blockIdx.x >> 5, m = blockIdx.x & 31;   // member m -> XCD m%8
    const int w = tid >> 6, L = tid & 63, lm = L & 15, q = L >> 4, lm7 = lm & 7;
    const int colbase = m * 32;
    const int cl = w * 16 + lm;
    const int rb = g * 16;
    uint16_t* hb = hb_all + (size_t)g * (8 * 16 * HID);   // 2 parity x 4 slots
    unsigned* ctr = ctr_all + g * 128;
    const floatx4 zero = {0.f, 0.f, 0.f, 0.f};

    // loop-invariant bias loads, hoisted out of the t-loop
    const float b1v = b1g[colbase + cl];
    const float b2v = b2g[colbase + cl];
    const float b3v = b3g[colbase + cl];
    const float b4v = b4g[colbase + cl];
    const float b5v = b5g[cl];
    float cbv[8];
    #pragma unroll
    for (int ct = 0; ct < 8; ct++) cbv[ct] = cb[w * 128 + ct * 16 + lm];

    // initial z: local LDS only (every member keeps its own copy), swizzled
    for (int idx = tid; idx < 16 * 256; idx += ARTHREADS) {
        int r = idx >> 8, c = idx & 255;
        zst[zswz(r, c)] = f2bf(zfinal[(size_t)(rb + r) * LAT + c]);
    }
    __syncthreads();

    // ARRIVE: wave0 publishes slice, drains its stores, lane0 RMWs counter.
    #define HOP_ARRIVE(DST) do {                                             \
        __syncthreads();                                                     \
        if (tid < 64) {                                                      \
            int row_ = tid >> 2, gr_ = tid & 3;                              \
            floatx4 vv_ = *(const floatx4*)((const char*)hsl + tid * 16);    \
            int gsw_ = (m * 4 + gr_) ^ (row_ & 7);                           \
            st16_mall((char*)(DST) + row_ * 2048 + gsw_ * 16, vv_);          \
            asm volatile("s_waitcnt vmcnt(0)" ::: "memory");                 \
            if (tid == 0)                                                    \
                __hip_atomic_fetch_add(ctr, 1u, __ATOMIC_RELAXED,            \
                                       __HIP_MEMORY_SCOPE_AGENT);            \
        }                                                                    \
    } while (0)

    // WAIT: tid0 spins on the group counter, then one block barrier.
    #define HOP_WAIT(TGT) do {                                               \
        if (tid == 0) {                                                      \
            while (__hip_atomic_load(ctr, __ATOMIC_RELAXED,                  \
                                     __HIP_MEMORY_SCOPE_AGENT) < (TGT)) {}   \
        }                                                                    \
        __syncthreads();                                                     \
    } while (0)

    // cell z-part chunk: kc in [K0,K1), accumulated into cc[8]
    #define CCZ(K0, K1) do {                                                 \
        _Pragma("unroll")                                                    \
        for (int ct = 0; ct < 8; ct++) {                                     \
            const uint16_t* bb2_ = wbc + (size_t)(w * 128 + ct * 16 + lm) * 288 + q * 8; \
            _Pragma("unroll")                                                \
            for (int kc = (K0); kc < (K1); kc++) {                           \
                int gz_ = (kc * 4 + q) ^ lm7;                                \
                short8 a_ = *(const short8*)(zcur + lm * 256 + gz_ * 8);     \
                short8 b_ = *(const short8*)(bb2_ + kc * 32);                \
                cc[ct] = __builtin_amdgcn_mfma_f32_16x16x32_bf16(a_, b_, cc[ct], 0, 0, 0); \
            }                                                                \
        }                                                                    \
    } while (0)

    #define MID_COMPUTE(WB, BV) do {                                         \
        floatx4 acc_ = zero;                                                 \
        const uint16_t* bb_ = WB + (size_t)(colbase + cl) * HID + q * 8;     \
        _Pragma("unroll 8")                                                  \
        for (int kc = 0; kc < 32; kc++) {                                    \
            int gh = (kc * 4 + q) ^ lm7;                                     \
            short8 a_ = *(const short8*)(hstg + lm * 1024 + gh * 8);         \
            short8 b_ = *(const short8*)(bb_ + kc * 32);                     \
            acc_ = __builtin_amdgcn_mfma_f32_16x16x32_bf16(a_, b_, acc_, 0, 0, 0); \
        }                                                                    \
        _Pragma("unroll")                                                    \
        for (int i = 0; i < 4; i++)                                          \
            hsl[(q * 4 + i) * 32 + cl] = f2bf(fmaxf(acc_[i] + (BV), 0.f));   \
    } while (0)

    unsigned tgt = 0;
    #pragma unroll 1
    for (int t = 0; t < HOR - TTF; t++) {
        uint16_t* zcur = zst + (t & 1) * (16 * 256);
        uint16_t* znx  = zst + ((t + 1) & 1) * (16 * 256);
        uint16_t* hp = hb + (t & 1) * (4 * 16 * HID);     // step-parity tiles
        uint16_t* h1 = hp;
        uint16_t* h2 = hp + 16 * HID;
        uint16_t* h3 = hp + 2 * 16 * HID;
        uint16_t* h4 = hp + 3 * 16 * HID;

        floatx4 cc[8];
        #pragma unroll
        for (int ct = 0; ct < 8; ct++) cc[ct] = zero;

        // ---- L1 slice from LDS z (local) ----
        {
            floatx4 acc = zero;
            const uint16_t* bb = wb1 + (size_t)(colbase + cl) * LAT + q * 8;
            #pragma unroll
            for (int kc = 0; kc < 8; kc++) {
                int gz = (kc * 4 + q) ^ lm7;
                short8 a = *(const short8*)(zcur + lm * 256 + gz * 8);
                short8 b = *(const short8*)(bb + kc * 32);
                acc = __builtin_amdgcn_mfma_f32_16x16x32_bf16(a, b, acc, 0, 0, 0);
            }
            #pragma unroll
            for (int i = 0; i < 4; i++)
                hsl[(q * 4 + i) * 32 + cl] = f2bf(fmaxf(acc[i] + b1v, 0.f));
        }
        HOP_ARRIVE(h1); tgt += MEMBERS;
        CCZ(0, 2);
        HOP_WAIT(tgt);
        stage_h(h1, hstg, w, L);
        __syncthreads();

        MID_COMPUTE(wb2, b2v);
        HOP_ARRIVE(h2); tgt += MEMBERS;
        CCZ(2, 4);
        HOP_WAIT(tgt);
        stage_h(h2, hstg, w, L);
        __syncthreads();

        MID_COMPUTE(wb3, b3v);
        HOP_ARRIVE(h3); tgt += MEMBERS;
        CCZ(4, 6);
        HOP_WAIT(tgt);
        stage_h(h3, hstg, w, L);
        __syncthreads();

        MID_COMPUTE(wb4, b4v);
        HOP_ARRIVE(h4); tgt += MEMBERS;
        CCZ(6, 8);
        HOP_WAIT(tgt);
        stage_h(h4, hstg, w, L);
        __syncthreads();

        // ---- tail: L5 (redundant), out, cell finish (yh term) ----
        {
            floatx4 a5 = zero;
            const uint16_t* bb = wb5 + (size_t)cl * HID + q * 8;
            #pragma unroll 8
            for (int kc = 0; kc < 32; kc++) {
                int gh = (kc * 4 + q) ^ lm7;
                short8 a = *(const short8*)(hstg + lm * 1024 + gh * 8);
                short8 b = *(const short8*)(bb + kc * 32);
                a5 = __builtin_amdgcn_mfma_f32_16x16x32_bf16(a, b, a5, 0, 0, 0);
            }
            float vout[4];
            #pragma unroll
            for (int i = 0; i < 4; i++) {
                float v = a5[i] + b5v;
                vout[i] = v;
                yscr[(q * 4 + i) * 32 + cl] = f2bf(v);
            }
            if (m == 0) {
                #pragma unroll
                for (int i = 0; i < 4; i++)
                    out[(size_t)(rb + q * 4 + i) * (HOR * OBS) + (TTF + t) * OBS + cl] = vout[i];
            }
        }
        __syncthreads();
        // cell finish: add the yh term (kc=8) to cc[], tanh, write z'
        {
            short8 ay = *(const short8*)(yscr + lm * 32 + q * 8);
            #pragma unroll
            for (int ct = 0; ct < 8; ct++) {
                int ccol = w * 128 + ct * 16 + lm;
                const uint16_t* bb2 = wbc + (size_t)ccol * 288 + q * 8;
                short8 b = *(const short8*)(bb2 + 8 * 32);
                floatx4 v = __builtin_amdgcn_mfma_f32_16x16x32_bf16(ay, b, cc[ct], 0, 0, 0);
                #pragma unroll
                for (int i = 0; i < 4; i++)
                    znx[zswz(q * 4 + i, ccol)] = f2bf(fast_tanh(v[i] + cbv[ct]));
            }
        }
        __syncthreads();
    }
    #undef MID_COMPUTE
    #undef CCZ
    #undef HOP_WAIT
    #undef HOP_ARRIVE
}

// ---------------------------------------------------------------------------
extern "C" void kernel_launch(void* const* d_in, const int* in_sizes, int n_in,
                              void* d_out, int out_size, void* d_ws, size_t ws_size,
                              hipStream_t stream) {
    (void)in_sizes; (void)n_in; (void)out_size;
    const float* y    = (const float*)d_in[0];
    const float* W_ih = (const float*)d_in[2];
    const float* W_hh = (const float*)d_in[3];
    const float* b_ih = (const float*)d_in[4];
    const float* b_hh = (const float*)d_in[5];
    const float* W1   = (const float*)d_in[6];
    const float* b1   = (const float*)d_in[7];
    const float* W2   = (const float*)d_in[8];
    const float* b2   = (const float*)d_in[9];
    const float* W3   = (const float*)d_in[10];
    const float* b3   = (const float*)d_in[11];
    const float* W4   = (const float*)d_in[12];
    const float* b4   = (const float*)d_in[13];
    const float* W5   = (const float*)d_in[14];
    const float* b5   = (const float*)d_in[15];
    float* out = (float*)d_out;
    char* ws = (char*)d_ws;

    uint16_t* WB1  = (uint16_t*)(ws + OFF_WB1);
    uint16_t* WB2  = (uint16_t*)(ws + OFF_WB2);
    uint16_t* WB3  = (uint16_t*)(ws + OFF_WB3);
    uint16_t* WB4  = (uint16_t*)(ws + OFF_WB4);
    uint16_t* WB5  = (uint16_t*)(ws + OFF_WB5);
    float*    CB   = (float*)(ws + OFF_CB);
    uint2*    WHH2 = (uint2*)(ws + OFF_WHH2);
    uint2*    WIH2 = (uint2*)(ws + OFF_WIH2);
    float*    ZF   = (float*)(ws + OFF_ZF);
    uint16_t* Zbuf = (uint16_t*)(ws + OFF_Z);
    uint16_t* WBC  = (uint16_t*)(ws + OFF_WBC);
    uint16_t* HB   = (uint16_t*)(ws + OFF_HB);
    unsigned* CTR  = (unsigned*)(ws + OFF_CTR);
    uint16_t* HA   = (uint16_t*)(ws + OFF_HA);
    uint16_t* HBF  = (uint16_t*)(ws + OFF_HBF);

    k_cvt<<<(HID*LAT + 255) / 256, 256, 0, stream>>>(W1, WB1, HID * LAT);
    k_cvt<<<(HID*HID + 255) / 256, 256, 0, stream>>>(W2, WB2, HID * HID);
    k_cvt<<<(HID*HID + 255) / 256, 256, 0, stream>>>(W3, WB3, HID * HID);
    k_cvt<<<(HID*HID + 255) / 256, 256, 0, stream>>>(W4, WB4, HID * HID);
    k_cvt<<<(OBS*HID + 255) / 256, 256, 0, stream>>>(W5, WB5, OBS * HID);
    k_cb<<<1, 256, 0, stream>>>(b_ih, b_hh, CB);
    k_pack<<<64, 256, 0, stream>>>(W_hh, WHH2, LAT);
    k_pack<<<8, 256, 0, stream>>>(W_ih, WIH2, OBS);
    k_packc<<<256, 256, 0, stream>>>(W_hh, W_ih, WBC);
    hipMemsetAsync(CTR, 0, GROUPS * 512, stream);

    k_rnn_tf<<<BATCH, 256, 0, stream>>>(y, WHH2, WIH2, CB, Zbuf, ZF);

    if (ws_size >= OFF_END) {
        // chunked per-layer psi GEMMs (XCD-pinned weight slices)
        const int NCHUNK = (BATCH * TTF) / PSI_CHUNK;   // 4
        for (int ch = 0; ch < NCHUNK; ch++) {
            const uint16_t* zin = Zbuf + (size_t)ch * PSI_CHUNK * LAT;
            k_psi_l1 <<<(PSI_CHUNK/32)*8, 512, 0, stream>>>(zin, WB1, b1, HA);
            k_psi_mid<<<(PSI_CHUNK/32)*8, 512, 0, stream>>>(HA, WB2, b2, HBF);
            k_psi_mid<<<(PSI_CHUNK/32)*8, 512, 0, stream>>>(HBF, WB3, b3, HA);
            k_psi_mid<<<(PSI_CHUNK/32)*8, 512, 0, stream>>>(HA, WB4, b4, HBF);
            k_psi_l5 <<<PSI_CHUNK/32, 128, 0, stream>>>(HBF, WB5, b5, out,
                                                        ch * PSI_CHUNK);
        }
    } else {
        k_psi_bulk<<<(BATCH * TTF) / 32, 512, 0, stream>>>(
            Zbuf, WB1, WB2, WB3, WB4, WB5, b1, b2, b3, b4, b5, out);
    }

    // Cooperative launch preferred (guaranteed co-residency); on ANY error
    // fall back to a plain launch — 256 blocks at 1+/CU are co-resident.
    void* args[] = {
        (void*)&ZF, (void*)&WB1, (void*)&WB2, (void*)&WB3, (void*)&WB4,
        (void*)&WB5, (void*)&WBC, (void*)&b1, (void*)&b2, (void*)&b3,
        (void*)&b4, (void*)&b5, (void*)&CB, (void*)&HB, (void*)&CTR,
        (void*)&out
    };
    hipError_t ce = hipLaunchCooperativeKernel((const void*)k_ar2,
                                               dim3(ARBLOCKS), dim3(ARTHREADS),
                                               args, 0, stream);
    if (ce != hipSuccess) {
        (void)hipGetLastError();   // clear sticky error
        k_ar2<<<dim3(ARBLOCKS), dim3(ARTHREADS), 0, stream>>>(
            ZF, WB1, WB2, WB3, WB4, WB5, WBC, b1, b2, b3, b4, b5, CB,
            HB, CTR, out);
    }
}

// Round 9
// 6277.152 us; speedup vs baseline: 1.3679x; 1.2626x over previous
//
#include <hip/hip_runtime.h>
#include <stdint.h>

// ---------------------------------------------------------------------------
// RNN rollout. Phase 1: teacher-forced recurrence + bulk psi. Phase 2:
// persistent AR kernel, 8 groups x 32 members, member m -> XCD m%8 (weight
// slices L2-resident, R6/R8). Failed variants (do not retry): co-located
// groups (R9), in-grid psi fusion (R11), redundant full-L1 (R12), epoch-flag
// exchange (R13), MALL-atomic L5 reduction (R15), chunked per-layer psi
// GEMMs (R16: global A-reads + scattered stores + 20 dependent launches =
// 2400us, 2x WORSE than monolithic psi_bulk's 1100us).
// AR kernel = R14 structure VERBATIM (4760-4800us steady, best known):
//   ARRIVE (publish 64x16B sc0|sc1 + drain + lane0 RMW) / overlap (cell
//   z-part, CCZ) / WAIT (tid0 spin + 1 syncthreads); tail = stage h4 + L5
//   redundant + cell finish; step-parity h tiles.
// R17 change: psi_bulk is weight-traffic-bound (1024 blocks x 6.5MB = 6.7GB
// at ~6TB/s). psi_bulk64 keeps the EXACT proven structure but processes 64
// rows/block (512 blocks, 128KB LDS h-buffer -- documented working on
// gfx950) => weight traffic halves. Address patterns identical (row&7 under
// rf*16 offsets == lm&7), math per row unchanged => bitwise-identical out.
// Fallback to 32-row psi_bulk on any synchronous launch error.
// Sizes fixed: B=128, T=256, HOR=512, OBS=32, LAT=256, HID=1024.
// ---------------------------------------------------------------------------

#define BATCH 128
#define TTF   256
#define HOR   512
#define OBS   32
#define LAT   256
#define HID   1024

#define GROUPS  8
#define MEMBERS 32
#define ARBLOCKS (GROUPS * MEMBERS)
#define ARTHREADS 128

typedef __attribute__((ext_vector_type(8))) short short8;
typedef __attribute__((ext_vector_type(4))) float floatx4;

// ---- workspace layout (bytes) ----
#define OFF_WB1   ((size_t)0)                          // 1024x256 bf16 ([col][k])
#define OFF_WB2   (OFF_WB1 + (size_t)HID*LAT*2)        // 1024x1024 bf16
#define OFF_WB3   (OFF_WB2 + (size_t)HID*HID*2)
#define OFF_WB4   (OFF_WB3 + (size_t)HID*HID*2)
#define OFF_WB5   (OFF_WB4 + (size_t)HID*HID*2)        // 32x1024 bf16
#define OFF_CB    (OFF_WB5 + (size_t)OBS*HID*2)        // 256 f32 (b_ih+b_hh)
#define OFF_WHH2  (OFF_CB + (size_t)LAT*4)             // 64x256 uint2 packed W_hh^T
#define OFF_WIH2  (OFF_WHH2 + (size_t)64*256*8)        // 8x256 uint2 packed W_ih^T
#define OFF_ZF    (OFF_WIH2 + (size_t)8*256*8)         // 128x256 f32
#define OFF_Z     (OFF_ZF + (size_t)BATCH*LAT*4)       // 32768x256 bf16
#define OFF_WBC   (OFF_Z + (size_t)BATCH*TTF*LAT*2)    // 256x288 bf16 cell matrix
#define OFF_HB    (OFF_WBC + (size_t)LAT*288*2)        // 8 x 2par x 4 x 16x1024 bf16
#define OFF_CTR   (OFF_HB + (size_t)GROUPS*8*16*HID*2) // 8 x 512B counters
#define OFF_END   (OFF_CTR + (size_t)GROUPS*512)

__device__ __forceinline__ uint16_t f2bf(float f) {
    uint32_t u = __float_as_uint(f);
    u += 0x7fffu + ((u >> 16) & 1u);   // RNE
    return (uint16_t)(u >> 16);
}
__device__ __forceinline__ float bflo(uint32_t u) { return __uint_as_float(u << 16); }
__device__ __forceinline__ float bfhi(uint32_t u) { return __uint_as_float(u & 0xffff0000u); }

__device__ __forceinline__ float fast_tanh(float x) {
    float ax = fabsf(x);
    float e  = __expf(-2.f * ax);
    float r  = (1.f - e) / (1.f + e);
    return copysignf(r, x);
}

// XOR-granule swizzles (16B granule index ^ low bits of row). Producers store
// swizzled; the verbatim DMA lands swizzled in LDS; readers XOR back.
__device__ __forceinline__ int hswz(int row, int col) {   // h: stride 1024
    return row * 1024 + ((((col >> 3) ^ (row & 7)) << 3) | (col & 7));
}
__device__ __forceinline__ int zswz(int row, int col) {   // z: stride 256
    return row * 256 + ((((col >> 3) ^ (row & 7)) << 3) | (col & 7));
}

// 16B MALL-coherent store (sc0|sc1 write-through, proven R9/R10).
__device__ __forceinline__ void st16_mall(void* p, floatx4 v) {
    asm volatile("global_store_dwordx4 %0, %1, off sc0 sc1"
                 :: "v"(p), "v"(v) : "memory");
}

// async DMA global->LDS, 16 B/lane, aux=0x11 (CPol SC0|SC1): reads at MALL
// (coherent with the sc0|sc1 writers), does not allocate into L1/L2.
typedef const __attribute__((address_space(1))) void* gas_t;
typedef __attribute__((address_space(3))) void* las_t;
__device__ __forceinline__ void gl_lds16(const void* g, void* l) {
    __builtin_amdgcn_global_load_lds((gas_t)g, (las_t)l, 16, 0, 0x11);
}

// 32 KB h tile MALL -> LDS: per wave 16 issues x 1 KB, all in flight.
__device__ __forceinline__ void stage_h(const uint16_t* src, uint16_t* dst,
                                        int w, int L) {
    const char* gp = (const char*)src + w * 16384 + L * 16;
    char* lp = (char*)dst + w * 16384;
    #pragma unroll
    for (int i = 0; i < 16; i++)
        gl_lds16(gp + i * 1024, lp + i * 1024);
}

// ---------------------------------------------------------------------------
// K0 helpers
// ---------------------------------------------------------------------------
__global__ void k_cvt(const float* __restrict__ s, uint16_t* __restrict__ d, int n) {
    int i = blockIdx.x * 256 + threadIdx.x;
    if (i < n) d[i] = f2bf(s[i]);
}

__global__ void k_cb(const float* __restrict__ a, const float* __restrict__ b,
                     float* __restrict__ c) {
    int j = threadIdx.x;
    c[j] = a[j] + b[j];
}

__global__ void k_pack(const float* __restrict__ w, uint2* __restrict__ dst, int klen) {
    int k4 = blockIdx.x, j = threadIdx.x;
    int k = k4 * 4;
    uint32_t a = f2bf(w[(size_t)j * klen + k + 0]);
    uint32_t b = f2bf(w[(size_t)j * klen + k + 1]);
    uint32_t c = f2bf(w[(size_t)j * klen + k + 2]);
    uint32_t d = f2bf(w[(size_t)j * klen + k + 3]);
    uint2 r; r.x = a | (b << 16); r.y = c | (d << 16);
    dst[k4 * 256 + j] = r;
}

__global__ void k_packc(const float* __restrict__ whh, const float* __restrict__ wih,
                        uint16_t* __restrict__ wbc) {
    int col = blockIdx.x;
    for (int k = threadIdx.x; k < 288; k += 256) {
        float v = (k < 256) ? whh[(size_t)col * 256 + k] : wih[(size_t)col * 32 + (k - 256)];
        wbc[(size_t)col * 288 + k] = f2bf(v);
    }
}

// ---------------------------------------------------------------------------
// K1: teacher-forced recurrence. 128 blocks x 256 threads.
// ---------------------------------------------------------------------------
__global__ __launch_bounds__(256) void k_rnn_tf(
    const float* __restrict__ y, const uint2* __restrict__ whh2,
    const uint2* __restrict__ wih2, const float* __restrict__ cb,
    uint16_t* __restrict__ Zg, float* __restrict__ zfinal)
{
    __shared__ alignas(16) float zl[LAT];
    __shared__ alignas(16) float ys[OBS];
    int j = threadIdx.x, b = blockIdx.x;
    zl[j] = 0.f;
    __syncthreads();
    const float4* z4 = (const float4*)zl;
    const float4* y4 = (const float4*)ys;
    for (int t = 0; t < TTF; t++) {
        if (j < OBS) ys[j] = y[(size_t)b * (TTF * OBS) + t * OBS + j];
        Zg[((size_t)b * TTF + t) * LAT + j] = f2bf(zl[j]);
        __syncthreads();
        float acc = cb[j];
        #pragma unroll 8
        for (int k4 = 0; k4 < 64; k4++) {
            uint2 wv = whh2[k4 * 256 + j];
            float4 zq = z4[k4];
            acc += bflo(wv.x) * zq.x + bfhi(wv.x) * zq.y
                 + bflo(wv.y) * zq.z + bfhi(wv.y) * zq.w;
        }
        #pragma unroll
        for (int k4 = 0; k4 < 8; k4++) {
            uint2 wv = wih2[k4 * 256 + j];
            float4 yq = y4[k4];
            acc += bflo(wv.x) * yq.x + bfhi(wv.x) * yq.y
                 + bflo(wv.y) * yq.z + bfhi(wv.y) * yq.w;
        }
        __syncthreads();
        zl[j] = fast_tanh(acc);
    }
    __syncthreads();
    zfinal[(size_t)b * LAT + j] = zl[j];
}

// ---------------------------------------------------------------------------
// K2 primary: bulk psi, 64 rows/block (512 blocks, 512 thr, 128KB LDS).
// Same structure/addressing as the proven 32-row psi_bulk; weight traffic
// halves. Wave w: cols [128w,128w+128), 4 row-frags.
// ---------------------------------------------------------------------------
__global__ __launch_bounds__(512) void k_psi_bulk64(
    const uint16_t* __restrict__ Zg,
    const uint16_t* __restrict__ wb1, const uint16_t* __restrict__ wb2,
    const uint16_t* __restrict__ wb3, const uint16_t* __restrict__ wb4,
    const uint16_t* __restrict__ wb5,
    const float* __restrict__ b1, const float* __restrict__ b2,
    const float* __restrict__ b3, const float* __restrict__ b4,
    const float* __restrict__ b5, float* __restrict__ out)
{
    __shared__ uint16_t hbuf[64 * 1024];   // 128 KB, swizzled
    int tid = threadIdx.x;
    int w = tid >> 6, L = tid & 63, lm = L & 15, q = L >> 4;
    int rb = blockIdx.x * 64;
    int colbase = w * 128;
    floatx4 acc[4][8];
    const floatx4 zero = {0.f, 0.f, 0.f, 0.f};

    #pragma unroll
    for (int rf = 0; rf < 4; rf++)
        #pragma unroll
        for (int nt = 0; nt < 8; nt++) acc[rf][nt] = zero;
    for (int kc = 0; kc < 8; kc++) {
        short8 a[4];
        #pragma unroll
        for (int rf = 0; rf < 4; rf++)
            a[rf] = *(const short8*)(Zg + (size_t)(rb + rf * 16 + lm) * LAT + kc * 32 + q * 8);
        #pragma unroll
        for (int nt = 0; nt < 8; nt++) {
            int n = colbase + nt * 16 + lm;
            short8 bf = *(const short8*)(wb1 + (size_t)n * LAT + kc * 32 + q * 8);
            #pragma unroll
            for (int rf = 0; rf < 4; rf++)
                acc[rf][nt] = __builtin_amdgcn_mfma_f32_16x16x32_bf16(a[rf], bf, acc[rf][nt], 0, 0, 0);
        }
    }
    #pragma unroll
    for (int rf = 0; rf < 4; rf++)
        #pragma unroll
        for (int nt = 0; nt < 8; nt++) {
            int col = colbase + nt * 16 + lm;
            float bias = b1[col];
            #pragma unroll
            for (int i = 0; i < 4; i++) {
                int row = rf * 16 + q * 4 + i;
                hbuf[hswz(row, col)] = f2bf(fmaxf(acc[rf][nt][i] + bias, 0.f));
            }
        }
    __syncthreads();

    const uint16_t* wbs[3] = {wb2, wb3, wb4};
    const float*    bbs[3] = {b2, b3, b4};
    for (int ll = 0; ll < 3; ll++) {
        const uint16_t* wb = wbs[ll];
        const float* bb = bbs[ll];
        #pragma unroll
        for (int rf = 0; rf < 4; rf++)
            #pragma unroll
            for (int nt = 0; nt < 8; nt++) acc[rf][nt] = zero;
        for (int kc = 0; kc < 32; kc++) {
            int g = ((kc * 4 + q) ^ (lm & 7)) << 3;
            short8 a[4];
            #pragma unroll
            for (int rf = 0; rf < 4; rf++)
                a[rf] = *(const short8*)(hbuf + (rf * 16 + lm) * 1024 + g);
            #pragma unroll
            for (int nt = 0; nt < 8; nt++) {
                int n = colbase + nt * 16 + lm;
                short8 bf = *(const short8*)(wb + (size_t)n * HID + kc * 32 + q * 8);
                #pragma unroll
                for (int rf = 0; rf < 4; rf++)
                    acc[rf][nt] = __builtin_amdgcn_mfma_f32_16x16x32_bf16(a[rf], bf, acc[rf][nt], 0, 0, 0);
            }
        }
        __syncthreads();
        #pragma unroll
        for (int rf = 0; rf < 4; rf++)
            #pragma unroll
            for (int nt = 0; nt < 8; nt++) {
                int col = colbase + nt * 16 + lm;
                float bias = bb[col];
                #pragma unroll
                for (int i = 0; i < 4; i++) {
                    int row = rf * 16 + q * 4 + i;
                    hbuf[hswz(row, col)] = f2bf(fmaxf(acc[rf][nt][i] + bias, 0.f));
                }
            }
        __syncthreads();
    }

    // L5: all 8 waves -- wave w = row-frag (w>>1) x col-tile (w&1)
    {
        int rf5 = w >> 1;
        int nb = (w & 1) * 16;
        floatx4 a5 = zero;
        for (int kc = 0; kc < 32; kc++) {
            int g = ((kc * 4 + q) ^ (lm & 7)) << 3;
            short8 a = *(const short8*)(hbuf + (rf5 * 16 + lm) * 1024 + g);
            short8 bf = *(const short8*)(wb5 + (size_t)(nb + lm) * HID + kc * 32 + q * 8);
            a5 = __builtin_amdgcn_mfma_f32_16x16x32_bf16(a, bf, a5, 0, 0, 0);
        }
        int col = nb + lm;
        float bias = b5[col];
        #pragma unroll
        for (int i = 0; i < 4; i++) {
            int r = rb + rf5 * 16 + q * 4 + i;
            int bb_ = r >> 8, tt = r & 255;
            out[(size_t)bb_ * (HOR * OBS) + tt * OBS + col] = a5[i] + bias;
        }
    }
}

// ---------------------------------------------------------------------------
// K2 fallback: bulk psi, 32 rows/block (R10-proven). Launched only if the
// 64-row variant is rejected at launch (synchronous error check).
// ---------------------------------------------------------------------------
__global__ __launch_bounds__(512) void k_psi_bulk(
    const uint16_t* __restrict__ Zg,
    const uint16_t* __restrict__ wb1, const uint16_t* __restrict__ wb2,
    const uint16_t* __restrict__ wb3, const uint16_t* __restrict__ wb4,
    const uint16_t* __restrict__ wb5,
    const float* __restrict__ b1, const float* __restrict__ b2,
    const float* __restrict__ b3, const float* __restrict__ b4,
    const float* __restrict__ b5, float* __restrict__ out)
{
    __shared__ uint16_t hbuf[32 * 1024];   // 64 KB, swizzled
    int tid = threadIdx.x;
    int w = tid >> 6, L = tid & 63, lm = L & 15, q = L >> 4;
    int rb = blockIdx.x * 32;
    int colbase = w * 128;
    floatx4 acc[2][8];
    const floatx4 zero = {0.f, 0.f, 0.f, 0.f};

    #pragma unroll
    for (int mt = 0; mt < 2; mt++)
        #pragma unroll
        for (int nt = 0; nt < 8; nt++) acc[mt][nt] = zero;
    for (int kc = 0; kc < 8; kc++) {
        short8 a0 = *(const short8*)(Zg + (size_t)(rb + lm) * LAT + kc * 32 + q * 8);
        short8 a1 = *(const short8*)(Zg + (size_t)(rb + 16 + lm) * LAT + kc * 32 + q * 8);
        #pragma unroll
        for (int nt = 0; nt < 8; nt++) {
            int n = colbase + nt * 16 + lm;
            short8 bf = *(const short8*)(wb1 + (size_t)n * LAT + kc * 32 + q * 8);
            acc[0][nt] = __builtin_amdgcn_mfma_f32_16x16x32_bf16(a0, bf, acc[0][nt], 0, 0, 0);
            acc[1][nt] = __builtin_amdgcn_mfma_f32_16x16x32_bf16(a1, bf, acc[1][nt], 0, 0, 0);
        }
    }
    #pragma unroll
    for (int mt = 0; mt < 2; mt++)
        #pragma unroll
        for (int nt = 0; nt < 8; nt++) {
            int col = colbase + nt * 16 + lm;
            float bias = b1[col];
            #pragma unroll
            for (int i = 0; i < 4; i++) {
                int row = mt * 16 + q * 4 + i;
                hbuf[hswz(row, col)] = f2bf(fmaxf(acc[mt][nt][i] + bias, 0.f));
            }
        }
    __syncthreads();

    const uint16_t* wbs[3] = {wb2, wb3, wb4};
    const float*    bbs[3] = {b2, b3, b4};
    for (int ll = 0; ll < 3; ll++) {
        const uint16_t* wb = wbs[ll];
        const float* bb = bbs[ll];
        #pragma unroll
        for (int mt = 0; mt < 2; mt++)
            #pragma unroll
            for (int nt = 0; nt < 8; nt++) acc[mt][nt] = zero;
        for (int kc = 0; kc < 32; kc++) {
            int g = ((kc * 4 + q) ^ (lm & 7)) << 3;
            short8 a0 = *(const short8*)(hbuf + lm * 1024 + g);
            short8 a1 = *(const short8*)(hbuf + (16 + lm) * 1024 + g);
            #pragma unroll
            for (int nt = 0; nt < 8; nt++) {
                int n = colbase + nt * 16 + lm;
                short8 bf = *(const short8*)(wb + (size_t)n * HID + kc * 32 + q * 8);
                acc[0][nt] = __builtin_amdgcn_mfma_f32_16x16x32_bf16(a0, bf, acc[0][nt], 0, 0, 0);
                acc[1][nt] = __builtin_amdgcn_mfma_f32_16x16x32_bf16(a1, bf, acc[1][nt], 0, 0, 0);
            }
        }
        __syncthreads();
        #pragma unroll
        for (int mt = 0; mt < 2; mt++)
            #pragma unroll
            for (int nt = 0; nt < 8; nt++) {
                int col = colbase + nt * 16 + lm;
                float bias = bb[col];
                #pragma unroll
                for (int i = 0; i < 4; i++) {
                    int row = mt * 16 + q * 4 + i;
                    hbuf[hswz(row, col)] = f2bf(fmaxf(acc[mt][nt][i] + bias, 0.f));
                }
            }
        __syncthreads();
    }

    if (w < 4) {
        int mt = w >> 1;
        int nb = (w & 1) * 16;
        floatx4 a5 = zero;
        for (int kc = 0; kc < 32; kc++) {
            int g = ((kc * 4 + q) ^ (lm & 7)) << 3;
            short8 a = *(const short8*)(hbuf + (mt * 16 + lm) * 1024 + g);
            short8 bf = *(const short8*)(wb5 + (size_t)(nb + lm) * HID + kc * 32 + q * 8);
            a5 = __builtin_amdgcn_mfma_f32_16x16x32_bf16(a, bf, a5, 0, 0, 0);
        }
        int col = nb + lm;
        float bias = b5[col];
        #pragma unroll
        for (int i = 0; i < 4; i++) {
            int row = mt * 16 + q * 4 + i;
            int r = rb + row;
            int bb_ = r >> 8, tt = r & 255;
            out[(size_t)bb_ * (HOR * OBS) + tt * OBS + col] = a5[i] + bias;
        }
    }
}

// ---------------------------------------------------------------------------
// K3 v14 (unchanged): persistent AR. R10 hop structure, counter barrier split
// into ARRIVE (publish + drain + lane0 RMW) / overlap (cell z-part) / WAIT
// (tid0 spin + one __syncthreads). Tail: stage h4, L5, out, cell finish.
// ---------------------------------------------------------------------------
__global__ __launch_bounds__(ARTHREADS) void k_ar2(
    const float* __restrict__ zfinal,
    const uint16_t* __restrict__ wb1, const uint16_t* __restrict__ wb2,
    const uint16_t* __restrict__ wb3, const uint16_t* __restrict__ wb4,
    const uint16_t* __restrict__ wb5, const uint16_t* __restrict__ wbc,
    const float* __restrict__ b1g, const float* __restrict__ b2g,
    const float* __restrict__ b3g, const float* __restrict__ b4g,
    const float* __restrict__ b5g, const float* __restrict__ cb,
    uint16_t* __restrict__ hb_all, unsigned* __restrict__ ctr_all,
    float* __restrict__ out)
{
    __shared__ alignas(16) uint16_t hstg[16 * 1024];   // 32 KB staged h tile
    __shared__ alignas(16) uint16_t zst[2 * 16 * 256]; // 16 KB z parity buffers
    __shared__ alignas(16) uint16_t yscr[16 * 32];     // 1 KB
    __shared__ alignas(16) uint16_t hsl[16 * 32];      // 1 KB slice transpose

    const int tid = threadIdx.x;
    const int g = blockIdx.x >> 5, m = blockIdx.x & 31;   // member m -> XCD m%8
    const int w = tid >> 6, L = tid & 63, lm = L & 15, q = L >> 4, lm7 = lm & 7;
    const int colbase = m * 32;
    const int cl = w * 16 + lm;
    const int rb = g * 16;
    uint16_t* hb = hb_all + (size_t)g * (8 * 16 * HID);   // 2 parity x 4 slots
    unsigned* ctr = ctr_all + g * 128;
    const floatx4 zero = {0.f, 0.f, 0.f, 0.f};

    // loop-invariant bias loads, hoisted out of the t-loop
    const float b1v = b1g[colbase + cl];
    const float b2v = b2g[colbase + cl];
    const float b3v = b3g[colbase + cl];
    const float b4v = b4g[colbase + cl];
    const float b5v = b5g[cl];
    float cbv[8];
    #pragma unroll
    for (int ct = 0; ct < 8; ct++) cbv[ct] = cb[w * 128 + ct * 16 + lm];

    // initial z: local LDS only (every member keeps its own copy), swizzled
    for (int idx = tid; idx < 16 * 256; idx += ARTHREADS) {
        int r = idx >> 8, c = idx & 255;
        zst[zswz(r, c)] = f2bf(zfinal[(size_t)(rb + r) * LAT + c]);
    }
    __syncthreads();

    // ARRIVE: wave0 publishes slice, drains its stores, lane0 RMWs counter.
    #define HOP_ARRIVE(DST) do {                                             \
        __syncthreads();                                                     \
        if (tid < 64) {                                                      \
            int row_ = tid >> 2, gr_ = tid & 3;                              \
            floatx4 vv_ = *(const floatx4*)((const char*)hsl + tid * 16);    \
            int gsw_ = (m * 4 + gr_) ^ (row_ & 7);                           \
            st16_mall((char*)(DST) + row_ * 2048 + gsw_ * 16, vv_);          \
            asm volatile("s_waitcnt vmcnt(0)" ::: "memory");                 \
            if (tid == 0)                                                    \
                __hip_atomic_fetch_add(ctr, 1u, __ATOMIC_RELAXED,            \
                                       __HIP_MEMORY_SCOPE_AGENT);            \
        }                                                                    \
    } while (0)

    // WAIT: tid0 spins on the group counter, then one block barrier.
    #define HOP_WAIT(TGT) do {                                               \
        if (tid == 0) {                                                      \
            while (__hip_atomic_load(ctr, __ATOMIC_RELAXED,                  \
                                     __HIP_MEMORY_SCOPE_AGENT) < (TGT)) {}   \
        }                                                                    \
        __syncthreads();                                                     \
    } while (0)

    // cell z-part chunk: kc in [K0,K1), accumulated into cc[8]
    #define CCZ(K0, K1) do {                                                 \
        _Pragma("unroll")                                                    \
        for (int ct = 0; ct < 8; ct++) {                                     \
            const uint16_t* bb2_ = wbc + (size_t)(w * 128 + ct * 16 + lm) * 288 + q * 8; \
            _Pragma("unroll")                                                \
            for (int kc = (K0); kc < (K1); kc++) {                           \
                int gz_ = (kc * 4 + q) ^ lm7;                                \
                short8 a_ = *(const short8*)(zcur + lm * 256 + gz_ * 8);     \
                short8 b_ = *(const short8*)(bb2_ + kc * 32);                \
                cc[ct] = __builtin_amdgcn_mfma_f32_16x16x32_bf16(a_, b_, cc[ct], 0, 0, 0); \
            }                                                                \
        }                                                                    \
    } while (0)

    #define MID_COMPUTE(WB, BV) do {                                         \
        floatx4 acc_ = zero;                                                 \
        const uint16_t* bb_ = WB + (size_t)(colbase + cl) * HID + q * 8;     \
        _Pragma("unroll 8")                                                  \
        for (int kc = 0; kc < 32; kc++) {                                    \
            int gh = (kc * 4 + q) ^ lm7;                                     \
            short8 a_ = *(const short8*)(hstg + lm * 1024 + gh * 8);         \
            short8 b_ = *(const short8*)(bb_ + kc * 32);                     \
            acc_ = __builtin_amdgcn_mfma_f32_16x16x32_bf16(a_, b_, acc_, 0, 0, 0); \
        }                                                                    \
        _Pragma("unroll")                                                    \
        for (int i = 0; i < 4; i++)                                          \
            hsl[(q * 4 + i) * 32 + cl] = f2bf(fmaxf(acc_[i] + (BV), 0.f));   \
    } while (0)

    unsigned tgt = 0;
    #pragma unroll 1
    for (int t = 0; t < HOR - TTF; t++) {
        uint16_t* zcur = zst + (t & 1) * (16 * 256);
        uint16_t* znx  = zst + ((t + 1) & 1) * (16 * 256);
        uint16_t* hp = hb + (t & 1) * (4 * 16 * HID);     // step-parity tiles
        uint16_t* h1 = hp;
        uint16_t* h2 = hp + 16 * HID;
        uint16_t* h3 = hp + 2 * 16 * HID;
        uint16_t* h4 = hp + 3 * 16 * HID;

        floatx4 cc[8];
        #pragma unroll
        for (int ct = 0; ct < 8; ct++) cc[ct] = zero;

        // ---- L1 slice from LDS z (local) ----
        {
            floatx4 acc = zero;
            const uint16_t* bb = wb1 + (size_t)(colbase + cl) * LAT + q * 8;
            #pragma unroll
            for (int kc = 0; kc < 8; kc++) {
                int gz = (kc * 4 + q) ^ lm7;
                short8 a = *(const short8*)(zcur + lm * 256 + gz * 8);
                short8 b = *(const short8*)(bb + kc * 32);
                acc = __builtin_amdgcn_mfma_f32_16x16x32_bf16(a, b, acc, 0, 0, 0);
            }
            #pragma unroll
            for (int i = 0; i < 4; i++)
                hsl[(q * 4 + i) * 32 + cl] = f2bf(fmaxf(acc[i] + b1v, 0.f));
        }
        HOP_ARRIVE(h1); tgt += MEMBERS;
        CCZ(0, 2);
        HOP_WAIT(tgt);
        stage_h(h1, hstg, w, L);
        __syncthreads();

        MID_COMPUTE(wb2, b2v);
        HOP_ARRIVE(h2); tgt += MEMBERS;
        CCZ(2, 4);
        HOP_WAIT(tgt);
        stage_h(h2, hstg, w, L);
        __syncthreads();

        MID_COMPUTE(wb3, b3v);
        HOP_ARRIVE(h3); tgt += MEMBERS;
        CCZ(4, 6);
        HOP_WAIT(tgt);
        stage_h(h3, hstg, w, L);
        __syncthreads();

        MID_COMPUTE(wb4, b4v);
        HOP_ARRIVE(h4); tgt += MEMBERS;
        CCZ(6, 8);
        HOP_WAIT(tgt);
        stage_h(h4, hstg, w, L);
        __syncthreads();

        // ---- tail: L5 (redundant), out, cell finish (yh term) ----
        {
            floatx4 a5 = zero;
            const uint16_t* bb = wb5 + (size_t)cl * HID + q * 8;
            #pragma unroll 8
            for (int kc = 0; kc < 32; kc++) {
                int gh = (kc * 4 + q) ^ lm7;
                short8 a = *(const short8*)(hstg + lm * 1024 + gh * 8);
                short8 b = *(const short8*)(bb + kc * 32);
                a5 = __builtin_amdgcn_mfma_f32_16x16x32_bf16(a, b, a5, 0, 0, 0);
            }
            float vout[4];
            #pragma unroll
            for (int i = 0; i < 4; i++) {
                float v = a5[i] + b5v;
                vout[i] = v;
                yscr[(q * 4 + i) * 32 + cl] = f2bf(v);
            }
            if (m == 0) {
                #pragma unroll
                for (int i = 0; i < 4; i++)
                    out[(size_t)(rb + q * 4 + i) * (HOR * OBS) + (TTF + t) * OBS + cl] = vout[i];
            }
        }
        __syncthreads();
        // cell finish: add the yh term (kc=8) to cc[], tanh, write z'
        {
            short8 ay = *(const short8*)(yscr + lm * 32 + q * 8);
            #pragma unroll
            for (int ct = 0; ct < 8; ct++) {
                int ccol = w * 128 + ct * 16 + lm;
                const uint16_t* bb2 = wbc + (size_t)ccol * 288 + q * 8;
                short8 b = *(const short8*)(bb2 + 8 * 32);
                floatx4 v = __builtin_amdgcn_mfma_f32_16x16x32_bf16(ay, b, cc[ct], 0, 0, 0);
                #pragma unroll
                for (int i = 0; i < 4; i++)
                    znx[zswz(q * 4 + i, ccol)] = f2bf(fast_tanh(v[i] + cbv[ct]));
            }
        }
        __syncthreads();
    }
    #undef MID_COMPUTE
    #undef CCZ
    #undef HOP_WAIT
    #undef HOP_ARRIVE
}

// ---------------------------------------------------------------------------
extern "C" void kernel_launch(void* const* d_in, const int* in_sizes, int n_in,
                              void* d_out, int out_size, void* d_ws, size_t ws_size,
                              hipStream_t stream) {
    (void)in_sizes; (void)n_in; (void)out_size; (void)ws_size;
    const float* y    = (const float*)d_in[0];
    const float* W_ih = (const float*)d_in[2];
    const float* W_hh = (const float*)d_in[3];
    const float* b_ih = (const float*)d_in[4];
    const float* b_hh = (const float*)d_in[5];
    const float* W1   = (const float*)d_in[6];
    const float* b1   = (const float*)d_in[7];
    const float* W2   = (const float*)d_in[8];
    const float* b2   = (const float*)d_in[9];
    const float* W3   = (const float*)d_in[10];
    const float* b3   = (const float*)d_in[11];
    const float* W4   = (const float*)d_in[12];
    const float* b4   = (const float*)d_in[13];
    const float* W5   = (const float*)d_in[14];
    const float* b5   = (const float*)d_in[15];
    float* out = (float*)d_out;
    char* ws = (char*)d_ws;

    uint16_t* WB1  = (uint16_t*)(ws + OFF_WB1);
    uint16_t* WB2  = (uint16_t*)(ws + OFF_WB2);
    uint16_t* WB3  = (uint16_t*)(ws + OFF_WB3);
    uint16_t* WB4  = (uint16_t*)(ws + OFF_WB4);
    uint16_t* WB5  = (uint16_t*)(ws + OFF_WB5);
    float*    CB   = (float*)(ws + OFF_CB);
    uint2*    WHH2 = (uint2*)(ws + OFF_WHH2);
    uint2*    WIH2 = (uint2*)(ws + OFF_WIH2);
    float*    ZF   = (float*)(ws + OFF_ZF);
    uint16_t* Zbuf = (uint16_t*)(ws + OFF_Z);
    uint16_t* WBC  = (uint16_t*)(ws + OFF_WBC);
    uint16_t* HB   = (uint16_t*)(ws + OFF_HB);
    unsigned* CTR  = (unsigned*)(ws + OFF_CTR);

    k_cvt<<<(HID*LAT + 255) / 256, 256, 0, stream>>>(W1, WB1, HID * LAT);
    k_cvt<<<(HID*HID + 255) / 256, 256, 0, stream>>>(W2, WB2, HID * HID);
    k_cvt<<<(HID*HID + 255) / 256, 256, 0, stream>>>(W3, WB3, HID * HID);
    k_cvt<<<(HID*HID + 255) / 256, 256, 0, stream>>>(W4, WB4, HID * HID);
    k_cvt<<<(OBS*HID + 255) / 256, 256, 0, stream>>>(W5, WB5, OBS * HID);
    k_cb<<<1, 256, 0, stream>>>(b_ih, b_hh, CB);
    k_pack<<<64, 256, 0, stream>>>(W_hh, WHH2, LAT);
    k_pack<<<8, 256, 0, stream>>>(W_ih, WIH2, OBS);
    k_packc<<<256, 256, 0, stream>>>(W_hh, W_ih, WBC);
    hipMemsetAsync(CTR, 0, GROUPS * 512, stream);

    k_rnn_tf<<<BATCH, 256, 0, stream>>>(y, WHH2, WIH2, CB, Zbuf, ZF);

    // psi: 64-row blocks (halved weight traffic); fall back to the proven
    // 32-row version on any synchronous launch error (e.g. LDS rejection).
    k_psi_bulk64<<<(BATCH * TTF) / 64, 512, 0, stream>>>(
        Zbuf, WB1, WB2, WB3, WB4, WB5, b1, b2, b3, b4, b5, out);
    hipError_t pe = hipGetLastError();
    if (pe != hipSuccess) {
        k_psi_bulk<<<(BATCH * TTF) / 32, 512, 0, stream>>>(
            Zbuf, WB1, WB2, WB3, WB4, WB5, b1, b2, b3, b4, b5, out);
    }

    // Cooperative launch preferred (guaranteed co-residency); on ANY error
    // fall back to a plain launch — 256 blocks at 1+/CU are co-resident.
    void* args[] = {
        (void*)&ZF, (void*)&WB1, (void*)&WB2, (void*)&WB3, (void*)&WB4,
        (void*)&WB5, (void*)&WBC, (void*)&b1, (void*)&b2, (void*)&b3,
        (void*)&b4, (void*)&b5, (void*)&CB, (void*)&HB, (void*)&CTR,
        (void*)&out
    };
    hipError_t ce = hipLaunchCooperativeKernel((const void*)k_ar2,
                                               dim3(ARBLOCKS), dim3(ARTHREADS),
                                               args, 0, stream);
    if (ce != hipSuccess) {
        (void)hipGetLastError();   // clear sticky error
        k_ar2<<<dim3(ARBLOCKS), dim3(ARTHREADS), 0, stream>>>(
            ZF, WB1, WB2, WB3, WB4, WB5, WBC, b1, b2, b3, b4, b5, CB,
            HB, CTR, out);
    }
}